// Round 2
// baseline (1016.256 us; speedup 1.0000x reference)
//
#include <hip/hip_runtime.h>
#include <hip/hip_bf16.h>

typedef __hip_bfloat16 bf16;

#define NTOT 32768   // 32*32*32 spatial positions
#define CH 64
#define PADV 39304   // 34*34*34
#define PROW 1156    // 34*34

__device__ __forceinline__ float bflo(unsigned int u){ union{unsigned int i;float f;}v; v.i=u<<16; return v.f; }
__device__ __forceinline__ float bfhi(unsigned int u){ union{unsigned int i;float f;}v; v.i=u&0xffff0000u; return v.f; }
__device__ __forceinline__ unsigned short f2bu(float f){ bf16 h = __float2bfloat16(f); unsigned short s; __builtin_memcpy(&s,&h,2); return s; }
__device__ __forceinline__ unsigned int pk2(float a, float b){ return (unsigned int)f2bu(a) | ((unsigned int)f2bu(b)<<16); }

__device__ __forceinline__ void load16(const bf16* p, float* o){
  const uint4* q = (const uint4*)p;
  uint4 u0 = q[0], u1 = q[1];
  o[0]=bflo(u0.x); o[1]=bfhi(u0.x); o[2]=bflo(u0.y); o[3]=bfhi(u0.y);
  o[4]=bflo(u0.z); o[5]=bfhi(u0.z); o[6]=bflo(u0.w); o[7]=bfhi(u0.w);
  o[8]=bflo(u1.x); o[9]=bfhi(u1.x); o[10]=bflo(u1.y); o[11]=bfhi(u1.y);
  o[12]=bflo(u1.z); o[13]=bfhi(u1.z); o[14]=bflo(u1.w); o[15]=bfhi(u1.w);
}
__device__ __forceinline__ void store16(bf16* p, const float* v){
  uint4 u0, u1;
  u0.x=pk2(v[0],v[1]); u0.y=pk2(v[2],v[3]); u0.z=pk2(v[4],v[5]); u0.w=pk2(v[6],v[7]);
  u1.x=pk2(v[8],v[9]); u1.y=pk2(v[10],v[11]); u1.z=pk2(v[12],v[13]); u1.w=pk2(v[14],v[15]);
  uint4* q=(uint4*)p; q[0]=u0; q[1]=u1;
}

// ---------------- fused LayerNorm + qkvv GEMM ----------------
// x: (C,N) fp32.  out qkvv: (N,256) bf16, row = [q|k|v_ca|v_sa] each 4h*16d
__global__ __launch_bounds__(256) void k_qkvv(const float* __restrict__ x,
    const float* __restrict__ lng, const float* __restrict__ lnb,
    const float* __restrict__ w, bf16* __restrict__ qkvv)
{
  __shared__ float A[64][132];     // [c][nn]  (LN'd in place)
  __shared__ float Bt[64][68];     // [jj][c]
  __shared__ float mean_s[128], rstd_s[128];
  __shared__ float g_s[64], b_s[64];
  int t = threadIdx.x;
  int n0 = blockIdx.x * 128;
  int j0 = blockIdx.y * 64;
  for (int idx = t; idx < 64*32; idx += 256) {   // 64 c x 32 float4 groups
    int c = idx >> 5, g = idx & 31;
    *(float4*)&A[c][g*4] = *(const float4*)(x + (size_t)c*NTOT + n0 + g*4);
  }
  for (int idx = t; idx < 64*16; idx += 256) {
    int jj = idx >> 4, g = idx & 15;
    *(float4*)&Bt[jj][g*4] = *(const float4*)(w + (size_t)(j0+jj)*64 + g*4);
  }
  if (t < 64) { g_s[t] = lng[t]; b_s[t] = lnb[t]; }
  __syncthreads();
  if (t < 128) {
    float s=0.f, ss=0.f;
    for (int c=0;c<64;c++){ float v=A[c][t]; s+=v; ss+=v*v; }
    float m = s*(1.f/64.f);
    float var = ss*(1.f/64.f) - m*m;
    mean_s[t]=m; rstd_s[t]=rsqrtf(var+1e-5f);
  }
  __syncthreads();
  for (int idx=t; idx<64*128; idx+=256){
    int c = idx >> 7, nn = idx & 127;
    A[c][nn] = (A[c][nn]-mean_s[nn])*rstd_s[nn]*g_s[c] + b_s[c];
  }
  __syncthreads();
  int tn = t & 15, tj = t >> 4;
  float acc[8][4];
  #pragma unroll
  for (int i=0;i<8;i++){ acc[i][0]=0;acc[i][1]=0;acc[i][2]=0;acc[i][3]=0; }
  for (int c=0;c<64;c++){
    float4 a0 = *(const float4*)&A[c][tn*8];
    float4 a1 = *(const float4*)&A[c][tn*8+4];
    float av[8] = {a0.x,a0.y,a0.z,a0.w,a1.x,a1.y,a1.z,a1.w};
    float bv[4];
    #pragma unroll
    for (int j=0;j<4;j++) bv[j] = Bt[tj*4+j][c];
    #pragma unroll
    for (int i=0;i<8;i++)
      #pragma unroll
      for (int j=0;j<4;j++) acc[i][j] += av[i]*bv[j];
  }
  #pragma unroll
  for (int i=0;i<8;i++){
    int n = n0 + tn*8 + i;
    ushort4 v;
    v.x = f2bu(acc[i][0]); v.y = f2bu(acc[i][1]); v.z = f2bu(acc[i][2]); v.w = f2bu(acc[i][3]);
    *(ushort4*)(qkvv + (size_t)n*256 + j0 + tj*4) = v;
  }
}

// ---------------- channel attention: partial Gram + norms ----------------
__global__ __launch_bounds__(256) void k_chanpart(const bf16* __restrict__ qkvv,
    float* __restrict__ G, float* __restrict__ NQ, float* __restrict__ NK)
{
  int h = blockIdx.y;
  int t = threadIdx.x; int d = t>>4, e = t&15;
  __shared__ float qs[128][16];
  __shared__ float ks[128][16];
  float acc=0.f, accq=0.f, acck=0.f;
  for (int stage=0; stage<4; ++stage){
    int n0 = blockIdx.x*512 + stage*128;
    __syncthreads();
    {
      int r = t>>1, half = t&1;
      const bf16* p = qkvv + (size_t)(n0+r)*256 + half*64 + h*16;
      float tmp[16]; load16(p, tmp);
      float* dst = half ? &ks[r][0] : &qs[r][0];
      #pragma unroll
      for (int i=0;i<16;i++) dst[i]=tmp[i];
    }
    __syncthreads();
    for (int i=0;i<128;i++){
      float qv = qs[i][d], kv = ks[i][e];
      acc += qv*kv;
      if (e==0) accq += qv*qv;
      if (e==1){ float kd = ks[i][d]; acck += kd*kd; }
    }
  }
  atomicAdd(&G[(h*16+d)*16+e], acc);
  if (e==0) atomicAdd(&NQ[h*16+d], accq);
  if (e==1) atomicAdd(&NK[h*16+d], acck);
}

__global__ void k_chanfin(const float* __restrict__ G, const float* __restrict__ NQ,
    const float* __restrict__ NK, const float* __restrict__ temp, float* __restrict__ ACA)
{
  int t = threadIdx.x; if (t>=64) return;
  int h = t>>4;
  float tp = temp[h];
  float nq = fmaxf(sqrtf(NQ[t]), 1e-12f);
  float s[16]; float mx=-3.0e38f;
  #pragma unroll
  for (int e=0;e<16;e++){
    float nk = fmaxf(sqrtf(NK[h*16+e]), 1e-12f);
    s[e] = G[t*16+e] / (nq*nk) * tp;
    mx = fmaxf(mx, s[e]);
  }
  float sum=0.f;
  #pragma unroll
  for (int e=0;e<16;e++){ s[e]=expf(s[e]-mx); sum+=s[e]; }
  float inv = 1.f/sum;
  #pragma unroll
  for (int e=0;e<16;e++) ACA[t*16+e] = s[e]*inv;
}

// ---------------- spatial window attention + channel apply ----------------
__global__ __launch_bounds__(256) void k_spatial(const bf16* __restrict__ qkvv,
    const float* __restrict__ ACA, const float* __restrict__ temp2,
    const float* __restrict__ rpb, const float* __restrict__ qemb,
    bf16* __restrict__ xsa, bf16* __restrict__ xca)
{
  __shared__ float aca_s[1024];
  __shared__ float rpb_s[108];
  __shared__ float qemb_s[64];
  int t = threadIdx.x;
  for (int i=t;i<1024;i+=256) aca_s[i]=ACA[i];
  if (t<108) rpb_s[t]=rpb[t];
  if (t<64) qemb_s[t]=qemb[t];
  __syncthreads();
  int lane = t & 63, h = t >> 6;
  int n = blockIdx.x*64 + lane;
  int a = n>>10, b=(n>>5)&31, c=n&31;
  float q[16]; load16(qkvv + (size_t)n*256 + h*16, q);
  float s2=0.f;
  #pragma unroll
  for (int d=0;d<16;d++) s2 += q[d]*q[d];
  float inv = 1.f/fmaxf(sqrtf(s2), 1e-12f);
  float st2 = log1pf(expf(temp2[h]));
  #pragma unroll
  for (int d=0;d<16;d++) q[d] = (q[d]*inv + qemb_s[h*16+d])*st2;
  float sc[27]; float mx = -3.0e38f;
  #pragma unroll
  for (int kk=0;kk<27;kk++){
    int da=kk/9-1, db=(kk/3)%3-1, dc=kk%3-1;
    int aa=a+da, bb=b+db, cc=c+dc;
    float s = -3.0e38f;
    if ((unsigned)aa<32u && (unsigned)bb<32u && (unsigned)cc<32u){
      int nn = n + da*1024 + db*32 + dc;
      float kv[16]; load16(qkvv + (size_t)nn*256 + 64 + h*16, kv);
      s = rpb_s[h*27+kk];
      #pragma unroll
      for (int d=0;d<16;d++) s += q[d]*kv[d];
    }
    sc[kk]=s; mx = fmaxf(mx, s);
  }
  float sum=0.f;
  #pragma unroll
  for (int kk=0;kk<27;kk++){ float e = expf(sc[kk]-mx); sc[kk]=e; sum+=e; }
  float invs = 1.f/sum;
  float o[16];
  #pragma unroll
  for (int d=0;d<16;d++) o[d]=0.f;
  #pragma unroll
  for (int kk=0;kk<27;kk++){
    int da=kk/9-1, db=(kk/3)%3-1, dc=kk%3-1;
    int aa=a+da, bb=b+db, cc=c+dc;
    if ((unsigned)aa<32u && (unsigned)bb<32u && (unsigned)cc<32u){
      int nn = n + da*1024 + db*32 + dc;
      float vv[16]; load16(qkvv + (size_t)nn*256 + 192 + h*16, vv);
      float p = sc[kk];
      #pragma unroll
      for (int d=0;d<16;d++) o[d] += p*vv[d];
    }
  }
  #pragma unroll
  for (int d=0;d<16;d++) o[d]*=invs;
  store16(xsa + ((size_t)h*NTOT + n)*16, o);
  float vca[16]; load16(qkvv + (size_t)n*256 + 128 + h*16, vca);
  float oc[16];
  #pragma unroll
  for (int d=0;d<16;d++){
    float s=0.f;
    #pragma unroll
    for (int e=0;e<16;e++) s += aca_s[(h*16+d)*16+e]*vca[e];
    oc[d]=s;
  }
  store16(xca + (size_t)n*64 + h*16, oc);
}

// ---------------- projections + gamma residual -> skip (C,N) fp32 ----------------
__global__ __launch_bounds__(256) void k_epilogue(const float* __restrict__ x,
    const bf16* __restrict__ xsa, const bf16* __restrict__ xca,
    const float* __restrict__ op1w, const float* __restrict__ op1b,
    const float* __restrict__ op2w, const float* __restrict__ op2b,
    const float* __restrict__ gamma, float* __restrict__ skip)
{
  __shared__ float w1[32][68];
  __shared__ float w2[32][68];
  __shared__ float b1s[32], b2s[32], gs[64];
  int t = threadIdx.x;
  for (int idx=t; idx<32*16; idx+=256){
    int cc=idx>>4, g=idx&15;
    *(float4*)&w1[cc][g*4] = *(const float4*)(op1w + (size_t)cc*64 + g*4);
    *(float4*)&w2[cc][g*4] = *(const float4*)(op2w + (size_t)cc*64 + g*4);
  }
  if (t<32){ b1s[t]=op1b[t]; b2s[t]=op2b[t]; }
  if (t<64) gs[t]=gamma[t];
  __syncthreads();
  int n = blockIdx.x*256 + t;
  float xs_[64], xc_[64];
  #pragma unroll
  for (int i=0;i<4;i++){ load16(xsa + (size_t)n*64 + i*16, xs_ + i*16); load16(xca + (size_t)n*64 + i*16, xc_ + i*16); }
  #pragma unroll 4
  for (int cc=0; cc<32; cc++){
    float s1=b1s[cc], s2v=b2s[cc];
    #pragma unroll
    for (int k4=0;k4<16;k4++){
      float4 wv1 = *(const float4*)&w1[cc][k4*4];
      float4 wv2 = *(const float4*)&w2[cc][k4*4];
      s1  += wv1.x*xs_[k4*4] + wv1.y*xs_[k4*4+1] + wv1.z*xs_[k4*4+2] + wv1.w*xs_[k4*4+3];
      s2v += wv2.x*xc_[k4*4] + wv2.y*xc_[k4*4+1] + wv2.z*xc_[k4*4+2] + wv2.w*xc_[k4*4+3];
    }
    skip[(size_t)cc*NTOT + n]      = x[(size_t)cc*NTOT+n]      + gs[cc]*s1;
    skip[(size_t)(32+cc)*NTOT + n] = x[(size_t)(32+cc)*NTOT+n] + gs[32+cc]*s2v;
  }
}

// ---------------- conv weight prep: fp32 (64,64,27) -> fp32 (64,64,28) ----------------
__global__ void k_wprep(const float* __restrict__ wA, const float* __restrict__ wB,
    const float* __restrict__ wC, const float* __restrict__ wD,
    const float* __restrict__ w8, float* __restrict__ wp, float* __restrict__ w8t)
{
  int idx = blockIdx.x*256 + threadIdx.x;
  if (idx < 16384){
    int which = idx >> 12; int pair = idx & 4095;
    const float* src = (which==0?wA:which==1?wB:which==2?wC:wD) + (size_t)pair*27;
    float* dst = wp + ((size_t)which*4096 + pair)*28;
    for (int o=0;o<27;o++) dst[o]=src[o];
    dst[27]=0.f;
  }
  if (idx < 4096){ int ci = idx>>6, co = idx&63; w8t[ci*64+co] = w8[(size_t)co*64+ci]; }
}

// ---------------- zero-pad (+optional BN+LReLU) -> (64,34,34,34) bf16 ----------------
__global__ __launch_bounds__(256) void k_pad(const float* __restrict__ src,
    const float* __restrict__ stats, const float* __restrict__ g, const float* __restrict__ be,
    bf16* __restrict__ xp, int mode)
{
  int idx = blockIdx.x*256+threadIdx.x;
  if (idx >= 64*PADV) return;
  int ci = idx / PADV; int r = idx % PADV;
  int pa = r/PROW, r2 = r%PROW, pb = r2/34, pc = r2%34;
  float v = 0.f;
  if (pa>=1 && pa<=32 && pb>=1 && pb<=32 && pc>=1 && pc<=32){
    v = src[(size_t)ci*NTOT + (pa-1)*1024 + (pb-1)*32 + (pc-1)];
    if (mode){
      float m=stats[ci*2], rs=stats[ci*2+1];
      v = (v-m)*rs*g[ci]+be[ci];
      v = v>0.f ? v : 0.01f*v;
    }
  }
  xp[idx] = __float2bfloat16(v);
}

// ---------------- direct 3x3x3 conv, padded input ----------------
__global__ __launch_bounds__(256) void k_conv3(const bf16* __restrict__ xp,
    const float* __restrict__ wp, const float* __restrict__ bias, float* __restrict__ Y)
{
  __shared__ float xs[16*9*36];   // [ci16][row9][36]
  int t = threadIdx.x;
  int a = blockIdx.x >> 5, b = blockIdx.x & 31;
  int co = t >> 2, wq = t & 3;
  float acc[8];
  #pragma unroll
  for (int j=0;j<8;j++) acc[j]=0.f;
  const float* wrow_base = wp + (size_t)co*64*28;
  for (int chunk=0; chunk<4; ++chunk){
    __syncthreads();
    for (int idx=t; idx<16*9*17; idx+=256){
      int ci = idx/(9*17); int rr = idx%(9*17); int row = rr/17; int p = rr%17;
      int da = row/3, db = row%3;
      unsigned int u = *(const unsigned int*)(xp + (size_t)(chunk*16+ci)*PADV + (size_t)(a+da)*PROW + (b+db)*34 + p*2);
      float* d = &xs[(ci*9 + row)*36];
      d[p*2]=bflo(u); d[p*2+1]=bfhi(u);
    }
    __syncthreads();
    for (int ci=0; ci<16; ++ci){
      const float* wr = wrow_base + (size_t)(chunk*16+ci)*28;
      float w28[28];
      #pragma unroll
      for (int q4=0;q4<7;q4++) *(float4*)&w28[q4*4] = *(const float4*)(wr + q4*4);
      #pragma unroll
      for (int row=0; row<9; ++row){
        const float* xrow = &xs[(ci*9+row)*36] + wq*8;
        float4 xa = *(const float4*)(xrow);
        float4 xb = *(const float4*)(xrow+4);
        float x8 = xrow[8], x9 = xrow[9];
        float xv[10] = {xa.x,xa.y,xa.z,xa.w,xb.x,xb.y,xb.z,xb.w,x8,x9};
        float w0 = w28[row*3+0], w1v = w28[row*3+1], w2v = w28[row*3+2];
        #pragma unroll
        for (int j=0;j<8;j++) acc[j] += w0*xv[j] + w1v*xv[j+1] + w2v*xv[j+2];
      }
    }
  }
  float bv = bias[co];
  size_t nbase = (size_t)a*1024 + b*32 + wq*8;
  float4 o0 = {acc[0]+bv, acc[1]+bv, acc[2]+bv, acc[3]+bv};
  float4 o1 = {acc[4]+bv, acc[5]+bv, acc[6]+bv, acc[7]+bv};
  *(float4*)(Y + (size_t)co*NTOT + nbase)     = o0;
  *(float4*)(Y + (size_t)co*NTOT + nbase + 4) = o1;
}

// ---------------- batchnorm stats ----------------
__global__ __launch_bounds__(256) void k_bnstats(const float* __restrict__ Y, float* __restrict__ stats)
{
  int ci = blockIdx.x;
  const float* p = Y + (size_t)ci*NTOT;
  float s=0.f, ss=0.f;
  for (int i=threadIdx.x; i<NTOT; i+=256){ float v=p[i]; s+=v; ss+=v*v; }
  for (int o=32;o;o>>=1){ s += __shfl_down(s,o); ss += __shfl_down(ss,o); }
  __shared__ float rs[4], rss[4];
  int w = threadIdx.x>>6;
  if ((threadIdx.x&63)==0){ rs[w]=s; rss[w]=ss; }
  __syncthreads();
  if (threadIdx.x==0){
    float S=rs[0]+rs[1]+rs[2]+rs[3], SS=rss[0]+rss[1]+rss[2]+rss[3];
    float m=S*(1.f/NTOT); float var=SS*(1.f/NTOT)-m*m;
    stats[ci*2]=m; stats[ci*2+1]=rsqrtf(var+1e-5f);
  }
}

// ---------------- BN + residual + LReLU ----------------
__global__ __launch_bounds__(256) void k_bnres(const float* __restrict__ Y, const float* __restrict__ stats,
    const float* __restrict__ g, const float* __restrict__ be,
    const float* __restrict__ skipin, float* __restrict__ out)
{
  size_t idx = (size_t)blockIdx.x*256 + threadIdx.x;
  int ci = (int)(idx >> 15);
  float m = stats[ci*2], rs = stats[ci*2+1];
  float v = (Y[idx]-m)*rs*g[ci] + be[ci] + skipin[idx];
  out[idx] = v>0.f ? v : 0.01f*v;
}

// ---------------- 1x1x1 conv + final residual -> fp32 out ----------------
__global__ __launch_bounds__(256) void k_conv1(const float* __restrict__ R, const float* __restrict__ w8t,
    const float* __restrict__ b8, const float* __restrict__ skip, float* __restrict__ out)
{
  __shared__ float wt[64][64];  // [ci][co]
  __shared__ float bs[64];
  int t = threadIdx.x;
  for (int idx=t; idx<4096; idx+=256) ((float*)wt)[idx] = w8t[idx];
  if (t<64) bs[t]=b8[t];
  __syncthreads();
  int lane = t&63, cg = t>>6;
  int n = blockIdx.x*64 + lane;
  float acc[16];
  #pragma unroll
  for (int j=0;j<16;j++) acc[j]=0.f;
  for (int ci=0; ci<64; ci++){
    float rv = R[(size_t)ci*NTOT + n];
    const float* wr = &wt[ci][cg*16];
    float4 wa = *(const float4*)(wr);
    float4 wb = *(const float4*)(wr+4);
    float4 wc = *(const float4*)(wr+8);
    float4 wd = *(const float4*)(wr+12);
    acc[0]+=rv*wa.x; acc[1]+=rv*wa.y; acc[2]+=rv*wa.z; acc[3]+=rv*wa.w;
    acc[4]+=rv*wb.x; acc[5]+=rv*wb.y; acc[6]+=rv*wb.z; acc[7]+=rv*wb.w;
    acc[8]+=rv*wc.x; acc[9]+=rv*wc.y; acc[10]+=rv*wc.z; acc[11]+=rv*wc.w;
    acc[12]+=rv*wd.x; acc[13]+=rv*wd.y; acc[14]+=rv*wd.z; acc[15]+=rv*wd.w;
  }
  #pragma unroll
  for (int j=0;j<16;j++){
    int co = cg*16+j;
    out[(size_t)co*NTOT + n] = acc[j] + bs[co] + skip[(size_t)co*NTOT+n];
  }
}

extern "C" void kernel_launch(void* const* d_in, const int* in_sizes, int n_in,
                              void* d_out, int out_size, void* d_ws, size_t ws_size,
                              hipStream_t stream) {
  (void)in_sizes; (void)n_in; (void)out_size; (void)ws_size;
  const float* x      = (const float*)d_in[0];
  const float* ln_g   = (const float*)d_in[1];
  const float* ln_b   = (const float*)d_in[2];
  const float* gamma  = (const float*)d_in[3];
  const float* qkvv_w = (const float*)d_in[4];
  const float* temp   = (const float*)d_in[5];
  const float* temp2  = (const float*)d_in[6];
  const float* rpb    = (const float*)d_in[7];
  const float* qemb   = (const float*)d_in[8];
  const float* op1w   = (const float*)d_in[9];
  const float* op1b   = (const float*)d_in[10];
  const float* op2w   = (const float*)d_in[11];
  const float* op2b   = (const float*)d_in[12];
  const float* c51_w1 = (const float*)d_in[13];
  const float* c51_b1 = (const float*)d_in[14];
  const float* c51_g1 = (const float*)d_in[15];
  const float* c51_be1= (const float*)d_in[16];
  const float* c51_w2 = (const float*)d_in[17];
  const float* c51_b2 = (const float*)d_in[18];
  const float* c51_g2 = (const float*)d_in[19];
  const float* c51_be2= (const float*)d_in[20];
  const float* c52_w1 = (const float*)d_in[21];
  const float* c52_b1 = (const float*)d_in[22];
  const float* c52_g1 = (const float*)d_in[23];
  const float* c52_be1= (const float*)d_in[24];
  const float* c52_w2 = (const float*)d_in[25];
  const float* c52_b2 = (const float*)d_in[26];
  const float* c52_g2 = (const float*)d_in[27];
  const float* c52_be2= (const float*)d_in[28];
  const float* c8_w   = (const float*)d_in[29];
  const float* c8_b   = (const float*)d_in[30];

  unsigned char* ws = (unsigned char*)d_ws;
  const size_t MB = 1u<<20;
  bf16*  qkvv = (bf16*)(ws + 0);              // 16 MB  (N,256)
  bf16*  xsa  = (bf16*)(ws + 16*MB);          // 4 MB
  bf16*  xca  = (bf16*)(ws + 20*MB);          // 4 MB
  float* skip = (float*)(ws + 24*MB);         // 8 MB
  float* stat = (float*)(ws + 32*MB);         // small
  float* G    = stat + 0;                     // 1024
  float* NQ   = stat + 1024;                  // 64
  float* NK   = stat + 1088;                  // 64
  float* ACA  = stat + 1152;                  // 1024
  float* BN   = stat + 2176;                  // 128
  float* wp   = (float*)(ws + 32*MB + 65536); // 4*4096*28 fp32 = 1.75MB
  float* w8t  = (float*)(ws + 32*MB + 65536 + 1835008); // 16KB
  bf16*  xp   = (bf16*)(ws + 0);              // 5.03MB (reuses qkvv after attention)
  float* Y    = (float*)(ws + 6*MB);          // 8MB
  float* Y2   = (float*)(ws + 14*MB);         // 8MB
  float* R    = (float*)(ws + 35*MB);         // 8MB -> peak 43MB

  hipMemsetAsync(stat, 0, 1152*sizeof(float), stream);
  k_wprep<<<64,256,0,stream>>>(c51_w1, c51_w2, c52_w1, c52_w2, c8_w, wp, w8t);
  k_qkvv<<<dim3(256,4),256,0,stream>>>(x, ln_g, ln_b, qkvv_w, qkvv);
  k_chanpart<<<dim3(64,4),256,0,stream>>>(qkvv, G, NQ, NK);
  k_chanfin<<<1,64,0,stream>>>(G, NQ, NK, temp, ACA);
  k_spatial<<<512,256,0,stream>>>(qkvv, ACA, temp2, rpb, qemb, xsa, xca);
  k_epilogue<<<128,256,0,stream>>>(x, xsa, xca, op1w, op1b, op2w, op2b, gamma, skip);
  // resblock 1
  k_pad<<<9826,256,0,stream>>>(skip, nullptr, nullptr, nullptr, xp, 0);
  k_conv3<<<1024,256,0,stream>>>(xp, wp + 0*114688, c51_b1, Y);
  k_bnstats<<<64,256,0,stream>>>(Y, BN);
  k_pad<<<9826,256,0,stream>>>(Y, BN, c51_g1, c51_be1, xp, 1);
  k_conv3<<<1024,256,0,stream>>>(xp, wp + 1*114688, c51_b2, Y2);
  k_bnstats<<<64,256,0,stream>>>(Y2, BN);
  k_bnres<<<8192,256,0,stream>>>(Y2, BN, c51_g2, c51_be2, skip, R);
  // resblock 2
  k_pad<<<9826,256,0,stream>>>(R, nullptr, nullptr, nullptr, xp, 0);
  k_conv3<<<1024,256,0,stream>>>(xp, wp + 2*114688, c52_b1, Y);
  k_bnstats<<<64,256,0,stream>>>(Y, BN);
  k_pad<<<9826,256,0,stream>>>(Y, BN, c52_g1, c52_be1, xp, 1);
  k_conv3<<<1024,256,0,stream>>>(xp, wp + 3*114688, c52_b2, Y2);
  k_bnstats<<<64,256,0,stream>>>(Y2, BN);
  k_bnres<<<8192,256,0,stream>>>(Y2, BN, c52_g2, c52_be2, R, R);
  // final 1x1x1 conv + residual
  k_conv1<<<512,256,0,stream>>>(R, w8t, c8_b, skip, (float*)d_out);
}

// Round 3
// 627.676 us; speedup vs baseline: 1.6191x; 1.6191x over previous
//
#include <hip/hip_runtime.h>
#include <hip/hip_bf16.h>

typedef __hip_bfloat16 bf16;
typedef __attribute__((ext_vector_type(8))) short s8v;
typedef __attribute__((ext_vector_type(4))) float f4v;

#define NTOT 32768   // 32*32*32 spatial positions
#define CH 64
#define PADV 39304   // 34*34*34
#define PROW 1156    // 34*34

__device__ __forceinline__ float bflo(unsigned int u){ union{unsigned int i;float f;}v; v.i=u<<16; return v.f; }
__device__ __forceinline__ float bfhi(unsigned int u){ union{unsigned int i;float f;}v; v.i=u&0xffff0000u; return v.f; }
__device__ __forceinline__ unsigned short f2bu(float f){ bf16 h = __float2bfloat16(f); unsigned short s; __builtin_memcpy(&s,&h,2); return s; }
__device__ __forceinline__ unsigned int pk2(float a, float b){ return (unsigned int)f2bu(a) | ((unsigned int)f2bu(b)<<16); }

__device__ __forceinline__ void load16(const bf16* p, float* o){
  const uint4* q = (const uint4*)p;
  uint4 u0 = q[0], u1 = q[1];
  o[0]=bflo(u0.x); o[1]=bfhi(u0.x); o[2]=bflo(u0.y); o[3]=bfhi(u0.y);
  o[4]=bflo(u0.z); o[5]=bfhi(u0.z); o[6]=bflo(u0.w); o[7]=bfhi(u0.w);
  o[8]=bflo(u1.x); o[9]=bfhi(u1.x); o[10]=bflo(u1.y); o[11]=bfhi(u1.y);
  o[12]=bflo(u1.z); o[13]=bfhi(u1.z); o[14]=bflo(u1.w); o[15]=bfhi(u1.w);
}
__device__ __forceinline__ void store16(bf16* p, const float* v){
  uint4 u0, u1;
  u0.x=pk2(v[0],v[1]); u0.y=pk2(v[2],v[3]); u0.z=pk2(v[4],v[5]); u0.w=pk2(v[6],v[7]);
  u1.x=pk2(v[8],v[9]); u1.y=pk2(v[10],v[11]); u1.z=pk2(v[12],v[13]); u1.w=pk2(v[14],v[15]);
  uint4* q=(uint4*)p; q[0]=u0; q[1]=u1;
}

// ---------------- fused LayerNorm + qkvv GEMM ----------------
__global__ __launch_bounds__(256) void k_qkvv(const float* __restrict__ x,
    const float* __restrict__ lng, const float* __restrict__ lnb,
    const float* __restrict__ w, bf16* __restrict__ qkvv)
{
  __shared__ float A[64][132];
  __shared__ float Bt[64][68];
  __shared__ float mean_s[128], rstd_s[128];
  __shared__ float g_s[64], b_s[64];
  int t = threadIdx.x;
  int n0 = blockIdx.x * 128;
  int j0 = blockIdx.y * 64;
  for (int idx = t; idx < 64*32; idx += 256) {
    int c = idx >> 5, g = idx & 31;
    *(float4*)&A[c][g*4] = *(const float4*)(x + (size_t)c*NTOT + n0 + g*4);
  }
  for (int idx = t; idx < 64*16; idx += 256) {
    int jj = idx >> 4, g = idx & 15;
    *(float4*)&Bt[jj][g*4] = *(const float4*)(w + (size_t)(j0+jj)*64 + g*4);
  }
  if (t < 64) { g_s[t] = lng[t]; b_s[t] = lnb[t]; }
  __syncthreads();
  if (t < 128) {
    float s=0.f, ss=0.f;
    for (int c=0;c<64;c++){ float v=A[c][t]; s+=v; ss+=v*v; }
    float m = s*(1.f/64.f);
    float var = ss*(1.f/64.f) - m*m;
    mean_s[t]=m; rstd_s[t]=rsqrtf(var+1e-5f);
  }
  __syncthreads();
  for (int idx=t; idx<64*128; idx+=256){
    int c = idx >> 7, nn = idx & 127;
    A[c][nn] = (A[c][nn]-mean_s[nn])*rstd_s[nn]*g_s[c] + b_s[c];
  }
  __syncthreads();
  int tn = t & 15, tj = t >> 4;
  float acc[8][4];
  #pragma unroll
  for (int i=0;i<8;i++){ acc[i][0]=0;acc[i][1]=0;acc[i][2]=0;acc[i][3]=0; }
  for (int c=0;c<64;c++){
    float4 a0 = *(const float4*)&A[c][tn*8];
    float4 a1 = *(const float4*)&A[c][tn*8+4];
    float av[8] = {a0.x,a0.y,a0.z,a0.w,a1.x,a1.y,a1.z,a1.w};
    float bv[4];
    #pragma unroll
    for (int j=0;j<4;j++) bv[j] = Bt[tj*4+j][c];
    #pragma unroll
    for (int i=0;i<8;i++)
      #pragma unroll
      for (int j=0;j<4;j++) acc[i][j] += av[i]*bv[j];
  }
  #pragma unroll
  for (int i=0;i<8;i++){
    int n = n0 + tn*8 + i;
    ushort4 v;
    v.x = f2bu(acc[i][0]); v.y = f2bu(acc[i][1]); v.z = f2bu(acc[i][2]); v.w = f2bu(acc[i][3]);
    *(ushort4*)(qkvv + (size_t)n*256 + j0 + tj*4) = v;
  }
}

// ---------------- channel attention: partial Gram + norms ----------------
__global__ __launch_bounds__(256) void k_chanpart(const bf16* __restrict__ qkvv,
    float* __restrict__ G, float* __restrict__ NQ, float* __restrict__ NK)
{
  int h = blockIdx.y;
  int t = threadIdx.x; int d = t>>4, e = t&15;
  __shared__ float qs[128][16];
  __shared__ float ks[128][16];
  float acc=0.f, accq=0.f, acck=0.f;
  for (int stage=0; stage<4; ++stage){
    int n0 = blockIdx.x*512 + stage*128;
    __syncthreads();
    {
      int r = t>>1, half = t&1;
      const bf16* p = qkvv + (size_t)(n0+r)*256 + half*64 + h*16;
      float tmp[16]; load16(p, tmp);
      float* dst = half ? &ks[r][0] : &qs[r][0];
      #pragma unroll
      for (int i=0;i<16;i++) dst[i]=tmp[i];
    }
    __syncthreads();
    for (int i=0;i<128;i++){
      float qv = qs[i][d], kv = ks[i][e];
      acc += qv*kv;
      if (e==0) accq += qv*qv;
      if (e==1){ float kd = ks[i][d]; acck += kd*kd; }
    }
  }
  atomicAdd(&G[(h*16+d)*16+e], acc);
  if (e==0) atomicAdd(&NQ[h*16+d], accq);
  if (e==1) atomicAdd(&NK[h*16+d], acck);
}

__global__ void k_chanfin(const float* __restrict__ G, const float* __restrict__ NQ,
    const float* __restrict__ NK, const float* __restrict__ temp, float* __restrict__ ACA)
{
  int t = threadIdx.x; if (t>=64) return;
  int h = t>>4;
  float tp = temp[h];
  float nq = fmaxf(sqrtf(NQ[t]), 1e-12f);
  float s[16]; float mx=-3.0e38f;
  #pragma unroll
  for (int e=0;e<16;e++){
    float nk = fmaxf(sqrtf(NK[h*16+e]), 1e-12f);
    s[e] = G[t*16+e] / (nq*nk) * tp;
    mx = fmaxf(mx, s[e]);
  }
  float sum=0.f;
  #pragma unroll
  for (int e=0;e<16;e++){ s[e]=expf(s[e]-mx); sum+=s[e]; }
  float inv = 1.f/sum;
  #pragma unroll
  for (int e=0;e<16;e++) ACA[t*16+e] = s[e]*inv;
}

// ---------------- spatial window attention + channel apply ----------------
__global__ __launch_bounds__(256) void k_spatial(const bf16* __restrict__ qkvv,
    const float* __restrict__ ACA, const float* __restrict__ temp2,
    const float* __restrict__ rpb, const float* __restrict__ qemb,
    bf16* __restrict__ xsa, bf16* __restrict__ xca)
{
  __shared__ float aca_s[1024];
  __shared__ float rpb_s[108];
  __shared__ float qemb_s[64];
  int t = threadIdx.x;
  for (int i=t;i<1024;i+=256) aca_s[i]=ACA[i];
  if (t<108) rpb_s[t]=rpb[t];
  if (t<64) qemb_s[t]=qemb[t];
  __syncthreads();
  int lane = t & 63, h = t >> 6;
  int n = blockIdx.x*64 + lane;
  int a = n>>10, b=(n>>5)&31, c=n&31;
  float q[16]; load16(qkvv + (size_t)n*256 + h*16, q);
  float s2=0.f;
  #pragma unroll
  for (int d=0;d<16;d++) s2 += q[d]*q[d];
  float inv = 1.f/fmaxf(sqrtf(s2), 1e-12f);
  float st2 = log1pf(expf(temp2[h]));
  #pragma unroll
  for (int d=0;d<16;d++) q[d] = (q[d]*inv + qemb_s[h*16+d])*st2;
  float sc[27]; float mx = -3.0e38f;
  #pragma unroll
  for (int kk=0;kk<27;kk++){
    int da=kk/9-1, db=(kk/3)%3-1, dc=kk%3-1;
    int aa=a+da, bb=b+db, cc=c+dc;
    float s = -3.0e38f;
    if ((unsigned)aa<32u && (unsigned)bb<32u && (unsigned)cc<32u){
      int nn = n + da*1024 + db*32 + dc;
      float kv[16]; load16(qkvv + (size_t)nn*256 + 64 + h*16, kv);
      s = rpb_s[h*27+kk];
      #pragma unroll
      for (int d=0;d<16;d++) s += q[d]*kv[d];
    }
    sc[kk]=s; mx = fmaxf(mx, s);
  }
  float sum=0.f;
  #pragma unroll
  for (int kk=0;kk<27;kk++){ float e = expf(sc[kk]-mx); sc[kk]=e; sum+=e; }
  float invs = 1.f/sum;
  float o[16];
  #pragma unroll
  for (int d=0;d<16;d++) o[d]=0.f;
  #pragma unroll
  for (int kk=0;kk<27;kk++){
    int da=kk/9-1, db=(kk/3)%3-1, dc=kk%3-1;
    int aa=a+da, bb=b+db, cc=c+dc;
    if ((unsigned)aa<32u && (unsigned)bb<32u && (unsigned)cc<32u){
      int nn = n + da*1024 + db*32 + dc;
      float vv[16]; load16(qkvv + (size_t)nn*256 + 192 + h*16, vv);
      float p = sc[kk];
      #pragma unroll
      for (int d=0;d<16;d++) o[d] += p*vv[d];
    }
  }
  #pragma unroll
  for (int d=0;d<16;d++) o[d]*=invs;
  store16(xsa + ((size_t)h*NTOT + n)*16, o);
  float vca[16]; load16(qkvv + (size_t)n*256 + 128 + h*16, vca);
  float oc[16];
  #pragma unroll
  for (int d=0;d<16;d++){
    float s=0.f;
    #pragma unroll
    for (int e=0;e<16;e++) s += aca_s[(h*16+d)*16+e]*vca[e];
    oc[d]=s;
  }
  store16(xca + (size_t)n*64 + h*16, oc);
}

// ---------------- projections + gamma residual -> skip (C,N) fp32 ----------------
__global__ __launch_bounds__(256) void k_epilogue(const float* __restrict__ x,
    const bf16* __restrict__ xsa, const bf16* __restrict__ xca,
    const float* __restrict__ op1w, const float* __restrict__ op1b,
    const float* __restrict__ op2w, const float* __restrict__ op2b,
    const float* __restrict__ gamma, float* __restrict__ skip)
{
  __shared__ float w1[32][68];
  __shared__ float w2[32][68];
  __shared__ float b1s[32], b2s[32], gs[64];
  int t = threadIdx.x;
  for (int idx=t; idx<32*16; idx+=256){
    int cc=idx>>4, g=idx&15;
    *(float4*)&w1[cc][g*4] = *(const float4*)(op1w + (size_t)cc*64 + g*4);
    *(float4*)&w2[cc][g*4] = *(const float4*)(op2w + (size_t)cc*64 + g*4);
  }
  if (t<32){ b1s[t]=op1b[t]; b2s[t]=op2b[t]; }
  if (t<64) gs[t]=gamma[t];
  __syncthreads();
  int n = blockIdx.x*256 + t;
  float xs_[64], xc_[64];
  #pragma unroll
  for (int i=0;i<4;i++){ load16(xsa + (size_t)n*64 + i*16, xs_ + i*16); load16(xca + (size_t)n*64 + i*16, xc_ + i*16); }
  #pragma unroll 4
  for (int cc=0; cc<32; cc++){
    float s1=b1s[cc], s2v=b2s[cc];
    #pragma unroll
    for (int k4=0;k4<16;k4++){
      float4 wv1 = *(const float4*)&w1[cc][k4*4];
      float4 wv2 = *(const float4*)&w2[cc][k4*4];
      s1  += wv1.x*xs_[k4*4] + wv1.y*xs_[k4*4+1] + wv1.z*xs_[k4*4+2] + wv1.w*xs_[k4*4+3];
      s2v += wv2.x*xc_[k4*4] + wv2.y*xc_[k4*4+1] + wv2.z*xc_[k4*4+2] + wv2.w*xc_[k4*4+3];
    }
    skip[(size_t)cc*NTOT + n]      = x[(size_t)cc*NTOT+n]      + gs[cc]*s1;
    skip[(size_t)(32+cc)*NTOT + n] = x[(size_t)(32+cc)*NTOT+n] + gs[32+cc]*s2v;
  }
}

// ---------------- conv weight prep: fp32 (64,64,27) -> bf16 WB[conv][co][k1792] ----------------
// k = cc*448 + tp*32 + q*8 + j ; tap = 2*tp + (q>>1) (27 => zero) ; ci = cc*16 + (q&1)*8 + j
__global__ void k_wprep(const float* __restrict__ wA, const float* __restrict__ wB_,
    const float* __restrict__ wC, const float* __restrict__ wD,
    const float* __restrict__ w8, bf16* __restrict__ WB, float* __restrict__ w8t)
{
  int idx = blockIdx.x*256 + threadIdx.x;
  if (idx < 458752){
    int conv = idx / 114688;
    int rem = idx - conv*114688;
    int co = rem / 1792;
    int k = rem - co*1792;
    int cc = k / 448; int r1 = k - cc*448;
    int tp = r1 >> 5; int qq = (r1 >> 3) & 3; int j = r1 & 7;
    int tap = 2*tp + (qq>>1);
    int ci = cc*16 + (qq&1)*8 + j;
    const float* src = conv==0?wA:conv==1?wB_:conv==2?wC:wD;
    float v = (tap < 27) ? src[((size_t)co*64 + ci)*27 + tap] : 0.f;
    WB[idx] = __float2bfloat16(v);
  }
  if (idx < 4096){ int ci = idx>>6, co = idx&63; w8t[ci*64+co] = w8[(size_t)co*64+ci]; }
}

// ---------------- pad+transpose (+optional BN+LReLU): (C,N) fp32 -> xpt[34^3][64] bf16 ----------------
__global__ __launch_bounds__(256) void k_padt(const float* __restrict__ src,
    const float* __restrict__ stats, const float* __restrict__ g, const float* __restrict__ be,
    bf16* __restrict__ xpt, int mode)
{
  __shared__ bf16 tile[32][68];
  int t = threadIdx.x;
  int n0 = blockIdx.x * 32;
  int nl = t & 31, cig = t >> 5;
  int n = n0 + nl;
  #pragma unroll
  for (int i=0;i<8;i++){
    int ci = cig*8 + i;
    float v = src[(size_t)ci*NTOT + n];
    if (mode){
      float m = stats[ci*2], rs = stats[ci*2+1];
      v = (v-m)*rs*g[ci] + be[ci];
      v = v>0.f ? v : 0.01f*v;
    }
    tile[nl][ci] = __float2bfloat16(v);
  }
  __syncthreads();
  int a = n0 >> 10, b = (n0 >> 5) & 31;
  size_t rowbase = ((size_t)((a+1)*34 + (b+1))*34 + 1)*64;
  #pragma unroll
  for (int k2=0;k2<2;k2++){
    int j = t + k2*256;
    int nn = j >> 4, grp = j & 15;
    uint2 val = *(const uint2*)&tile[nn][grp*4];
    *(uint2*)((unsigned char*)xpt + (rowbase + (size_t)nn*64 + grp*4)*2) = val;
  }
}

// ---------------- MFMA implicit-GEMM 3x3x3 conv ----------------
// grid 256: wg -> a = bx>>3, b0 = (bx&7)*4. 128 pos x 64 co, K=1792.
__global__ __launch_bounds__(256) void k_conv3m(const bf16* __restrict__ xpt,
    const bf16* __restrict__ WB, const float* __restrict__ bias, float* __restrict__ Y)
{
  __shared__ uint4 smem4[2112];           // 33792 B: staging 29376 B / epilogue 33792 B
  unsigned char* smb = (unsigned char*)smem4;
  float* smf = (float*)smem4;
  int t = threadIdx.x;
  int w = t >> 6, lane = t & 63;
  int r = lane & 15, q = lane >> 4;
  int qe = q & 1, qh = q >> 1;
  int a = blockIdx.x >> 3, b0 = (blockIdx.x & 7) * 4;

  int toff[14];
  #pragma unroll
  for (int tp = 0; tp < 14; ++tp) {
    int tap = 2*tp + qh;
    int da = tap/9, rem = tap - da*9, db = rem/3, dc = rem - db*3;
    toff[tp] = (tap < 27) ? (((da*6+db)*34 + dc)*48) : 0;
  }
  int F0 = (w*34 + r)*48 + qe*16;
  int F1 = F0 + 16*48;
  size_t bbyte = ((size_t)r*1792 + q*8)*2;

  f4v acc[2][4];
  #pragma unroll
  for (int mt=0;mt<2;mt++)
    #pragma unroll
    for (int nt=0;nt<4;nt++){ acc[mt][nt][0]=0.f; acc[mt][nt][1]=0.f; acc[mt][nt][2]=0.f; acc[mt][nt][3]=0.f; }

  for (int cc = 0; cc < 4; ++cc) {
    __syncthreads();
    // stage 16-ci chunk: 612 positions x 32B -> LDS [s][48B stride]
    uint4 tmp[5]; int dsts[5];
    #pragma unroll
    for (int k5 = 0; k5 < 5; ++k5) {
      int idx = t + k5*256;
      if (idx < 1224) {
        int row = idx / 68, rr = idx - row*68;
        int pc = rr >> 1, half = rr & 1;
        int par = row / 6;
        int pa = a + par, pb = b0 + row - par*6;
        size_t gb = ((size_t)((pa*34+pb)*34 + pc))*128 + cc*32 + half*16;
        tmp[k5] = *(const uint4*)((const unsigned char*)xpt + gb);
        dsts[k5] = (row*34 + pc)*3 + half;
      } else dsts[k5] = -1;
    }
    #pragma unroll
    for (int k5 = 0; k5 < 5; ++k5) if (dsts[k5] >= 0) smem4[dsts[k5]] = tmp[k5];
    __syncthreads();
    size_t kbase = (size_t)cc*448*2;
    #pragma unroll
    for (int tp = 0; tp < 14; ++tp) {
      s8v a0 = *(const s8v*)(smb + F0 + toff[tp]);
      s8v a1 = *(const s8v*)(smb + F1 + toff[tp]);
      size_t kb = bbyte + kbase + tp*64;
      s8v bv0 = *(const s8v*)((const unsigned char*)WB + kb);
      s8v bv1 = *(const s8v*)((const unsigned char*)WB + kb + 57344);
      s8v bv2 = *(const s8v*)((const unsigned char*)WB + kb + 114688);
      s8v bv3 = *(const s8v*)((const unsigned char*)WB + kb + 172032);
      acc[0][0] = __builtin_amdgcn_mfma_f32_16x16x32_bf16(a0, bv0, acc[0][0], 0, 0, 0);
      acc[0][1] = __builtin_amdgcn_mfma_f32_16x16x32_bf16(a0, bv1, acc[0][1], 0, 0, 0);
      acc[0][2] = __builtin_amdgcn_mfma_f32_16x16x32_bf16(a0, bv2, acc[0][2], 0, 0, 0);
      acc[0][3] = __builtin_amdgcn_mfma_f32_16x16x32_bf16(a0, bv3, acc[0][3], 0, 0, 0);
      acc[1][0] = __builtin_amdgcn_mfma_f32_16x16x32_bf16(a1, bv0, acc[1][0], 0, 0, 0);
      acc[1][1] = __builtin_amdgcn_mfma_f32_16x16x32_bf16(a1, bv1, acc[1][1], 0, 0, 0);
      acc[1][2] = __builtin_amdgcn_mfma_f32_16x16x32_bf16(a1, bv2, acc[1][2], 0, 0, 0);
      acc[1][3] = __builtin_amdgcn_mfma_f32_16x16x32_bf16(a1, bv3, acc[1][3], 0, 0, 0);
    }
  }
  // epilogue: transpose via LDS, coalesced store + bias
  __syncthreads();
  #pragma unroll
  for (int mt=0; mt<2; ++mt)
    #pragma unroll
    for (int nt=0; nt<4; ++nt)
      #pragma unroll
      for (int reg=0; reg<4; ++reg)
        smf[w*2112 + (nt*16+r)*33 + mt*16 + q*4 + reg] = acc[mt][nt][reg];
  __syncthreads();
  int c = lane & 31, cop = lane >> 5;
  size_t nb = (size_t)a*1024 + (size_t)(b0+w)*32;
  #pragma unroll
  for (int i=0;i<32;i++){
    int co = i*2 + cop;
    Y[(size_t)co*NTOT + nb + c] = smf[w*2112 + co*33 + c] + bias[co];
  }
}

// ---------------- batchnorm stats ----------------
__global__ __launch_bounds__(256) void k_bnstats(const float* __restrict__ Y, float* __restrict__ stats)
{
  int ci = blockIdx.x;
  const float* p = Y + (size_t)ci*NTOT;
  float s=0.f, ss=0.f;
  for (int i=threadIdx.x; i<NTOT; i+=256){ float v=p[i]; s+=v; ss+=v*v; }
  for (int o=32;o;o>>=1){ s += __shfl_down(s,o); ss += __shfl_down(ss,o); }
  __shared__ float rs[4], rss[4];
  int w = threadIdx.x>>6;
  if ((threadIdx.x&63)==0){ rs[w]=s; rss[w]=ss; }
  __syncthreads();
  if (threadIdx.x==0){
    float S=rs[0]+rs[1]+rs[2]+rs[3], SS=rss[0]+rss[1]+rss[2]+rss[3];
    float m=S*(1.f/NTOT); float var=SS*(1.f/NTOT)-m*m;
    stats[ci*2]=m; stats[ci*2+1]=rsqrtf(var+1e-5f);
  }
}

// ---------------- BN + residual + LReLU ----------------
__global__ __launch_bounds__(256) void k_bnres(const float* __restrict__ Y, const float* __restrict__ stats,
    const float* __restrict__ g, const float* __restrict__ be,
    const float* __restrict__ skipin, float* __restrict__ out)
{
  size_t idx = (size_t)blockIdx.x*256 + threadIdx.x;
  int ci = (int)(idx >> 15);
  float m = stats[ci*2], rs = stats[ci*2+1];
  float v = (Y[idx]-m)*rs*g[ci] + be[ci] + skipin[idx];
  out[idx] = v>0.f ? v : 0.01f*v;
}

// ---------------- 1x1x1 conv + final residual -> fp32 out ----------------
__global__ __launch_bounds__(256) void k_conv1(const float* __restrict__ R, const float* __restrict__ w8t,
    const float* __restrict__ b8, const float* __restrict__ skip, float* __restrict__ out)
{
  __shared__ float wt[64][64];
  __shared__ float bs[64];
  int t = threadIdx.x;
  for (int idx=t; idx<4096; idx+=256) ((float*)wt)[idx] = w8t[idx];
  if (t<64) bs[t]=b8[t];
  __syncthreads();
  int lane = t&63, cg = t>>6;
  int n = blockIdx.x*64 + lane;
  float acc[16];
  #pragma unroll
  for (int j=0;j<16;j++) acc[j]=0.f;
  for (int ci=0; ci<64; ci++){
    float rv = R[(size_t)ci*NTOT + n];
    const float* wr = &wt[ci][cg*16];
    float4 wa = *(const float4*)(wr);
    float4 wb = *(const float4*)(wr+4);
    float4 wc = *(const float4*)(wr+8);
    float4 wd = *(const float4*)(wr+12);
    acc[0]+=rv*wa.x; acc[1]+=rv*wa.y; acc[2]+=rv*wa.z; acc[3]+=rv*wa.w;
    acc[4]+=rv*wb.x; acc[5]+=rv*wb.y; acc[6]+=rv*wb.z; acc[7]+=rv*wb.w;
    acc[8]+=rv*wc.x; acc[9]+=rv*wc.y; acc[10]+=rv*wc.z; acc[11]+=rv*wc.w;
    acc[12]+=rv*wd.x; acc[13]+=rv*wd.y; acc[14]+=rv*wd.z; acc[15]+=rv*wd.w;
  }
  #pragma unroll
  for (int j=0;j<16;j++){
    int co = cg*16+j;
    out[(size_t)co*NTOT + n] = acc[j] + bs[co] + skip[(size_t)co*NTOT+n];
  }
}

extern "C" void kernel_launch(void* const* d_in, const int* in_sizes, int n_in,
                              void* d_out, int out_size, void* d_ws, size_t ws_size,
                              hipStream_t stream) {
  (void)in_sizes; (void)n_in; (void)out_size; (void)ws_size;
  const float* x      = (const float*)d_in[0];
  const float* ln_g   = (const float*)d_in[1];
  const float* ln_b   = (const float*)d_in[2];
  const float* gamma  = (const float*)d_in[3];
  const float* qkvv_w = (const float*)d_in[4];
  const float* temp   = (const float*)d_in[5];
  const float* temp2  = (const float*)d_in[6];
  const float* rpb    = (const float*)d_in[7];
  const float* qemb   = (const float*)d_in[8];
  const float* op1w   = (const float*)d_in[9];
  const float* op1b   = (const float*)d_in[10];
  const float* op2w   = (const float*)d_in[11];
  const float* op2b   = (const float*)d_in[12];
  const float* c51_w1 = (const float*)d_in[13];
  const float* c51_b1 = (const float*)d_in[14];
  const float* c51_g1 = (const float*)d_in[15];
  const float* c51_be1= (const float*)d_in[16];
  const float* c51_w2 = (const float*)d_in[17];
  const float* c51_b2 = (const float*)d_in[18];
  const float* c51_g2 = (const float*)d_in[19];
  const float* c51_be2= (const float*)d_in[20];
  const float* c52_w1 = (const float*)d_in[21];
  const float* c52_b1 = (const float*)d_in[22];
  const float* c52_g1 = (const float*)d_in[23];
  const float* c52_be1= (const float*)d_in[24];
  const float* c52_w2 = (const float*)d_in[25];
  const float* c52_b2 = (const float*)d_in[26];
  const float* c52_g2 = (const float*)d_in[27];
  const float* c52_be2= (const float*)d_in[28];
  const float* c8_w   = (const float*)d_in[29];
  const float* c8_b   = (const float*)d_in[30];

  unsigned char* ws = (unsigned char*)d_ws;
  const size_t MB = 1u<<20;
  bf16*  qkvv = (bf16*)(ws + 0);              // 16 MB  (N,256)
  bf16*  xsa  = (bf16*)(ws + 16*MB);          // 4 MB
  bf16*  xca  = (bf16*)(ws + 20*MB);          // 4 MB
  float* skip = (float*)(ws + 24*MB);         // 8 MB
  float* stat = (float*)(ws + 32*MB);         // small
  float* G    = stat + 0;                     // 1024
  float* NQ   = stat + 1024;                  // 64
  float* NK   = stat + 1088;                  // 64
  float* ACA  = stat + 1152;                  // 1024
  float* BN   = stat + 2176;                  // 128
  bf16*  WB   = (bf16*)(ws + 32*MB + 65536);  // 4*64*1792 bf16 = 896KB
  float* w8t  = (float*)(ws + 32*MB + 65536 + 1835008); // 16KB
  bf16*  xpt  = (bf16*)(ws + 0);              // 5.03MB transposed padded (reuses qkvv)
  float* Y    = (float*)(ws + 6*MB);          // 8MB
  float* Y2   = (float*)(ws + 14*MB);         // 8MB
  float* R    = (float*)(ws + 35*MB);         // 8MB -> peak 43MB

  hipMemsetAsync(stat, 0, 1152*sizeof(float), stream);
  k_wprep<<<1792,256,0,stream>>>(c51_w1, c51_w2, c52_w1, c52_w2, c8_w, WB, w8t);
  k_qkvv<<<dim3(256,4),256,0,stream>>>(x, ln_g, ln_b, qkvv_w, qkvv);
  k_chanpart<<<dim3(64,4),256,0,stream>>>(qkvv, G, NQ, NK);
  k_chanfin<<<1,64,0,stream>>>(G, NQ, NK, temp, ACA);
  k_spatial<<<512,256,0,stream>>>(qkvv, ACA, temp2, rpb, qemb, xsa, xca);
  k_epilogue<<<128,256,0,stream>>>(x, xsa, xca, op1w, op1b, op2w, op2b, gamma, skip);
  // zero the padded borders once (interior rewritten by each k_padt)
  hipMemsetAsync(xpt, 0, (size_t)PADV*64*2, stream);
  // resblock 1
  k_padt<<<1024,256,0,stream>>>(skip, nullptr, nullptr, nullptr, xpt, 0);
  k_conv3m<<<256,256,0,stream>>>(xpt, WB + 0*114688, c51_b1, Y);
  k_bnstats<<<64,256,0,stream>>>(Y, BN);
  k_padt<<<1024,256,0,stream>>>(Y, BN, c51_g1, c51_be1, xpt, 1);
  k_conv3m<<<256,256,0,stream>>>(xpt, WB + 1*114688, c51_b2, Y2);
  k_bnstats<<<64,256,0,stream>>>(Y2, BN);
  k_bnres<<<8192,256,0,stream>>>(Y2, BN, c51_g2, c51_be2, skip, R);
  // resblock 2
  k_padt<<<1024,256,0,stream>>>(R, nullptr, nullptr, nullptr, xpt, 0);
  k_conv3m<<<256,256,0,stream>>>(xpt, WB + 2*114688, c52_b1, Y);
  k_bnstats<<<64,256,0,stream>>>(Y, BN);
  k_padt<<<1024,256,0,stream>>>(Y, BN, c52_g1, c52_be1, xpt, 1);
  k_conv3m<<<256,256,0,stream>>>(xpt, WB + 3*114688, c52_b2, Y2);
  k_bnstats<<<64,256,0,stream>>>(Y2, BN);
  k_bnres<<<8192,256,0,stream>>>(Y2, BN, c52_g2, c52_be2, R, R);
  // final 1x1x1 conv + residual
  k_conv1<<<512,256,0,stream>>>(R, w8t, c8_b, skip, (float*)d_out);
}

// Round 4
// 457.586 us; speedup vs baseline: 2.2209x; 1.3717x over previous
//
#include <hip/hip_runtime.h>
#include <hip/hip_bf16.h>

typedef __hip_bfloat16 bf16;
typedef __attribute__((ext_vector_type(8))) short s8v;
typedef __attribute__((ext_vector_type(4))) float f4v;

#define NTOT 32768   // 32*32*32 spatial positions
#define CH 64
#define PADV 39304   // 34*34*34
#define PROW 1156    // 34*34

__device__ __forceinline__ float bflo(unsigned int u){ union{unsigned int i;float f;}v; v.i=u<<16; return v.f; }
__device__ __forceinline__ float bfhi(unsigned int u){ union{unsigned int i;float f;}v; v.i=u&0xffff0000u; return v.f; }
__device__ __forceinline__ unsigned short f2bu(float f){ bf16 h = __float2bfloat16(f); unsigned short s; __builtin_memcpy(&s,&h,2); return s; }
__device__ __forceinline__ unsigned int pk2(float a, float b){ return (unsigned int)f2bu(a) | ((unsigned int)f2bu(b)<<16); }

__device__ __forceinline__ void load8(const bf16* p, float* o){
  uint4 u = *(const uint4*)p;
  o[0]=bflo(u.x); o[1]=bfhi(u.x); o[2]=bflo(u.y); o[3]=bfhi(u.y);
  o[4]=bflo(u.z); o[5]=bfhi(u.z); o[6]=bflo(u.w); o[7]=bfhi(u.w);
}
__device__ __forceinline__ void load16(const bf16* p, float* o){
  const uint4* q = (const uint4*)p;
  uint4 u0 = q[0], u1 = q[1];
  o[0]=bflo(u0.x); o[1]=bfhi(u0.x); o[2]=bflo(u0.y); o[3]=bfhi(u0.y);
  o[4]=bflo(u0.z); o[5]=bfhi(u0.z); o[6]=bflo(u0.w); o[7]=bfhi(u0.w);
  o[8]=bflo(u1.x); o[9]=bfhi(u1.x); o[10]=bflo(u1.y); o[11]=bfhi(u1.y);
  o[12]=bflo(u1.z); o[13]=bfhi(u1.z); o[14]=bflo(u1.w); o[15]=bfhi(u1.w);
}
__device__ __forceinline__ void store16(bf16* p, const float* v){
  uint4 u0, u1;
  u0.x=pk2(v[0],v[1]); u0.y=pk2(v[2],v[3]); u0.z=pk2(v[4],v[5]); u0.w=pk2(v[6],v[7]);
  u1.x=pk2(v[8],v[9]); u1.y=pk2(v[10],v[11]); u1.z=pk2(v[12],v[13]); u1.w=pk2(v[14],v[15]);
  uint4* q=(uint4*)p; q[0]=u0; q[1]=u1;
}

// ---------------- fused LayerNorm + qkvv GEMM ----------------
__global__ __launch_bounds__(256) void k_qkvv(const float* __restrict__ x,
    const float* __restrict__ lng, const float* __restrict__ lnb,
    const float* __restrict__ w, bf16* __restrict__ qkvv)
{
  __shared__ float A[64][132];
  __shared__ float Bt[64][68];
  __shared__ float mean_s[128], rstd_s[128];
  __shared__ float g_s[64], b_s[64];
  int t = threadIdx.x;
  int n0 = blockIdx.x * 128;
  int j0 = blockIdx.y * 64;
  for (int idx = t; idx < 64*32; idx += 256) {
    int c = idx >> 5, g = idx & 31;
    *(float4*)&A[c][g*4] = *(const float4*)(x + (size_t)c*NTOT + n0 + g*4);
  }
  for (int idx = t; idx < 64*16; idx += 256) {
    int jj = idx >> 4, g = idx & 15;
    *(float4*)&Bt[jj][g*4] = *(const float4*)(w + (size_t)(j0+jj)*64 + g*4);
  }
  if (t < 64) { g_s[t] = lng[t]; b_s[t] = lnb[t]; }
  __syncthreads();
  if (t < 128) {
    float s=0.f, ss=0.f;
    for (int c=0;c<64;c++){ float v=A[c][t]; s+=v; ss+=v*v; }
    float m = s*(1.f/64.f);
    float var = ss*(1.f/64.f) - m*m;
    mean_s[t]=m; rstd_s[t]=rsqrtf(var+1e-5f);
  }
  __syncthreads();
  for (int idx=t; idx<64*128; idx+=256){
    int c = idx >> 7, nn = idx & 127;
    A[c][nn] = (A[c][nn]-mean_s[nn])*rstd_s[nn]*g_s[c] + b_s[c];
  }
  __syncthreads();
  int tn = t & 15, tj = t >> 4;
  float acc[8][4];
  #pragma unroll
  for (int i=0;i<8;i++){ acc[i][0]=0;acc[i][1]=0;acc[i][2]=0;acc[i][3]=0; }
  for (int c=0;c<64;c++){
    float4 a0 = *(const float4*)&A[c][tn*8];
    float4 a1 = *(const float4*)&A[c][tn*8+4];
    float av[8] = {a0.x,a0.y,a0.z,a0.w,a1.x,a1.y,a1.z,a1.w};
    float bv[4];
    #pragma unroll
    for (int j=0;j<4;j++) bv[j] = Bt[tj*4+j][c];
    #pragma unroll
    for (int i=0;i<8;i++)
      #pragma unroll
      for (int j=0;j<4;j++) acc[i][j] += av[i]*bv[j];
  }
  #pragma unroll
  for (int i=0;i<8;i++){
    int n = n0 + tn*8 + i;
    ushort4 v;
    v.x = f2bu(acc[i][0]); v.y = f2bu(acc[i][1]); v.z = f2bu(acc[i][2]); v.w = f2bu(acc[i][3]);
    *(ushort4*)(qkvv + (size_t)n*256 + j0 + tj*4) = v;
  }
}

// ---------------- channel attention: partial Gram + norms ----------------
__global__ __launch_bounds__(256) void k_chanpart(const bf16* __restrict__ qkvv,
    float* __restrict__ G, float* __restrict__ NQ, float* __restrict__ NK)
{
  int h = blockIdx.y;
  int t = threadIdx.x; int d = t>>4, e = t&15;
  __shared__ float qs[128][16];
  __shared__ float ks[128][16];
  float acc=0.f, accq=0.f, acck=0.f;
  for (int stage=0; stage<4; ++stage){
    int n0 = blockIdx.x*512 + stage*128;
    __syncthreads();
    {
      int r = t>>1, half = t&1;
      const bf16* p = qkvv + (size_t)(n0+r)*256 + half*64 + h*16;
      float tmp[16]; load16(p, tmp);
      float* dst = half ? &ks[r][0] : &qs[r][0];
      #pragma unroll
      for (int i=0;i<16;i++) dst[i]=tmp[i];
    }
    __syncthreads();
    for (int i=0;i<128;i++){
      float qv = qs[i][d], kv = ks[i][e];
      acc += qv*kv;
      if (e==0) accq += qv*qv;
      if (e==1){ float kd = ks[i][d]; acck += kd*kd; }
    }
  }
  atomicAdd(&G[(h*16+d)*16+e], acc);
  if (e==0) atomicAdd(&NQ[h*16+d], accq);
  if (e==1) atomicAdd(&NK[h*16+d], acck);
}

__global__ void k_chanfin(const float* __restrict__ G, const float* __restrict__ NQ,
    const float* __restrict__ NK, const float* __restrict__ temp, float* __restrict__ ACA)
{
  int t = threadIdx.x; if (t>=64) return;
  int h = t>>4;
  float tp = temp[h];
  float nq = fmaxf(sqrtf(NQ[t]), 1e-12f);
  float s[16]; float mx=-3.0e38f;
  #pragma unroll
  for (int e=0;e<16;e++){
    float nk = fmaxf(sqrtf(NK[h*16+e]), 1e-12f);
    s[e] = G[t*16+e] / (nq*nk) * tp;
    mx = fmaxf(mx, s[e]);
  }
  float sum=0.f;
  #pragma unroll
  for (int e=0;e<16;e++){ s[e]=expf(s[e]-mx); sum+=s[e]; }
  float inv = 1.f/sum;
  #pragma unroll
  for (int e=0;e<16;e++) ACA[t*16+e] = s[e]*inv;
}

// ---------------- spatial window attention + channel apply ----------------
__global__ __launch_bounds__(256) void k_spatial(const bf16* __restrict__ qkvv,
    const float* __restrict__ ACA, const float* __restrict__ temp2,
    const float* __restrict__ rpb, const float* __restrict__ qemb,
    bf16* __restrict__ xsa, bf16* __restrict__ xca)
{
  __shared__ float aca_s[1024];
  __shared__ float rpb_s[108];
  __shared__ float qemb_s[64];
  int t = threadIdx.x;
  for (int i=t;i<1024;i+=256) aca_s[i]=ACA[i];
  if (t<108) rpb_s[t]=rpb[t];
  if (t<64) qemb_s[t]=qemb[t];
  __syncthreads();
  int lane = t & 63, h = t >> 6;
  int n = blockIdx.x*64 + lane;
  int a = n>>10, b=(n>>5)&31, c=n&31;
  float q[16]; load16(qkvv + (size_t)n*256 + h*16, q);
  float s2=0.f;
  #pragma unroll
  for (int d=0;d<16;d++) s2 += q[d]*q[d];
  float inv = 1.f/fmaxf(sqrtf(s2), 1e-12f);
  float st2 = log1pf(expf(temp2[h]));
  #pragma unroll
  for (int d=0;d<16;d++) q[d] = (q[d]*inv + qemb_s[h*16+d])*st2;
  float sc[27]; float mx = -3.0e38f;
  #pragma unroll
  for (int kk=0;kk<27;kk++){
    int da=kk/9-1, db=(kk/3)%3-1, dc=kk%3-1;
    int aa=a+da, bb=b+db, cc=c+dc;
    float s = -3.0e38f;
    if ((unsigned)aa<32u && (unsigned)bb<32u && (unsigned)cc<32u){
      int nn = n + da*1024 + db*32 + dc;
      float kv[16]; load16(qkvv + (size_t)nn*256 + 64 + h*16, kv);
      s = rpb_s[h*27+kk];
      #pragma unroll
      for (int d=0;d<16;d++) s += q[d]*kv[d];
    }
    sc[kk]=s; mx = fmaxf(mx, s);
  }
  float sum=0.f;
  #pragma unroll
  for (int kk=0;kk<27;kk++){ float e = expf(sc[kk]-mx); sc[kk]=e; sum+=e; }
  float invs = 1.f/sum;
  float o[16];
  #pragma unroll
  for (int d=0;d<16;d++) o[d]=0.f;
  #pragma unroll
  for (int kk=0;kk<27;kk++){
    int da=kk/9-1, db=(kk/3)%3-1, dc=kk%3-1;
    int aa=a+da, bb=b+db, cc=c+dc;
    if ((unsigned)aa<32u && (unsigned)bb<32u && (unsigned)cc<32u){
      int nn = n + da*1024 + db*32 + dc;
      float vv[16]; load16(qkvv + (size_t)nn*256 + 192 + h*16, vv);
      float p = sc[kk];
      #pragma unroll
      for (int d=0;d<16;d++) o[d] += p*vv[d];
    }
  }
  #pragma unroll
  for (int d=0;d<16;d++) o[d]*=invs;
  store16(xsa + ((size_t)h*NTOT + n)*16, o);
  float vca[16]; load16(qkvv + (size_t)n*256 + 128 + h*16, vca);
  float oc[16];
  #pragma unroll
  for (int d=0;d<16;d++){
    float s=0.f;
    #pragma unroll
    for (int e=0;e<16;e++) s += aca_s[(h*16+d)*16+e]*vca[e];
    oc[d]=s;
  }
  store16(xca + (size_t)n*64 + h*16, oc);
}

// ---------------- projections + gamma residual -> skip (C,N) fp32 ----------------
// 512 blocks x 256 thr; block = 64 positions. Thread: one co (0..63) x 16 pos.
__global__ __launch_bounds__(256) void k_epilogue(const float* __restrict__ x,
    const bf16* __restrict__ xsa, const bf16* __restrict__ xca,
    const float* __restrict__ op1w, const float* __restrict__ op1b,
    const float* __restrict__ op2w, const float* __restrict__ op2b,
    const float* __restrict__ gamma, float* __restrict__ skip)
{
  __shared__ float xs_s[64][68];
  __shared__ float xc_s[64][68];
  int t = threadIdx.x;
  int n0 = blockIdx.x * 64;
  #pragma unroll
  for (int it=0; it<2; ++it){
    int idx = t + it*256;
    int p = idx >> 3, cg = idx & 7;
    float a8[8], c8[8];
    load8(xsa + (size_t)(n0+p)*64 + cg*8, a8);
    load8(xca + (size_t)(n0+p)*64 + cg*8, c8);
    #pragma unroll
    for (int i=0;i<8;i++){ xs_s[p][cg*8+i]=a8[i]; xc_s[p][cg*8+i]=c8[i]; }
  }
  int co = t & 63, pg = t >> 6;
  const float* wrow = (co < 32) ? (op1w + (size_t)co*64) : (op2w + (size_t)(co-32)*64);
  float wreg[64];
  #pragma unroll
  for (int i=0;i<16;i++) *(float4*)&wreg[i*4] = *(const float4*)(wrow + i*4);
  float bv = (co<32) ? op1b[co] : op2b[co-32];
  float gv = gamma[co];
  __syncthreads();
  const float* xt = (co<32) ? &xs_s[0][0] : &xc_s[0][0];
  float out16[16];
  #pragma unroll
  for (int i=0;i<16;i++){
    int p = pg*16 + i;
    const float* xr = xt + p*68;
    float s = bv;
    #pragma unroll
    for (int k4=0;k4<16;k4++){
      float4 xv = *(const float4*)(xr + k4*4);
      s += wreg[k4*4]*xv.x + wreg[k4*4+1]*xv.y + wreg[k4*4+2]*xv.z + wreg[k4*4+3]*xv.w;
    }
    out16[i] = s;
  }
  size_t base = (size_t)co*NTOT + n0 + pg*16;
  #pragma unroll
  for (int i4=0;i4<4;i4++){
    float4 xv = *(const float4*)(x + base + i4*4);
    float4 ov;
    ov.x = xv.x + gv*out16[i4*4];
    ov.y = xv.y + gv*out16[i4*4+1];
    ov.z = xv.z + gv*out16[i4*4+2];
    ov.w = xv.w + gv*out16[i4*4+3];
    *(float4*)(skip + base + i4*4) = ov;
  }
}

// ---------------- conv weight prep: fp32 (64,64,27) -> bf16 WB[conv][co][k1792] ----------------
__global__ void k_wprep(const float* __restrict__ wA, const float* __restrict__ wB_,
    const float* __restrict__ wC, const float* __restrict__ wD,
    const float* __restrict__ w8, bf16* __restrict__ WB, float* __restrict__ w8t)
{
  int idx = blockIdx.x*256 + threadIdx.x;
  if (idx < 458752){
    int conv = idx / 114688;
    int rem = idx - conv*114688;
    int co = rem / 1792;
    int k = rem - co*1792;
    int cc = k / 448; int r1 = k - cc*448;
    int tp = r1 >> 5; int qq = (r1 >> 3) & 3; int j = r1 & 7;
    int tap = 2*tp + (qq>>1);
    int ci = cc*16 + (qq&1)*8 + j;
    const float* src = conv==0?wA:conv==1?wB_:conv==2?wC:wD;
    float v = (tap < 27) ? src[((size_t)co*64 + ci)*27 + tap] : 0.f;
    WB[idx] = __float2bfloat16(v);
  }
  if (idx < 4096){ int ci = idx>>6, co = idx&63; w8t[ci*64+co] = w8[(size_t)co*64+ci]; }
}

// ---------------- pad+transpose (+optional BN+LReLU): (C,N) fp32 -> xpt[34^3][64] bf16 ----------------
__global__ __launch_bounds__(256) void k_padt(const float* __restrict__ src,
    const float* __restrict__ stats, const float* __restrict__ g, const float* __restrict__ be,
    bf16* __restrict__ xpt, int mode)
{
  __shared__ bf16 tile[32][68];
  int t = threadIdx.x;
  int n0 = blockIdx.x * 32;
  int nl = t & 31, cig = t >> 5;
  int n = n0 + nl;
  #pragma unroll
  for (int i=0;i<8;i++){
    int ci = cig*8 + i;
    float v = src[(size_t)ci*NTOT + n];
    if (mode){
      float S = stats[ci*2], SS = stats[ci*2+1];
      float m = S*(1.f/NTOT);
      float rs = rsqrtf(SS*(1.f/NTOT) - m*m + 1e-5f);
      v = (v-m)*rs*g[ci] + be[ci];
      v = v>0.f ? v : 0.01f*v;
    }
    tile[nl][ci] = __float2bfloat16(v);
  }
  __syncthreads();
  int a = n0 >> 10, b = (n0 >> 5) & 31;
  size_t rowbase = ((size_t)((a+1)*34 + (b+1))*34 + 1)*64;
  #pragma unroll
  for (int k2=0;k2<2;k2++){
    int j = t + k2*256;
    int nn = j >> 4, grp = j & 15;
    uint2 val = *(const uint2*)&tile[nn][grp*4];
    *(uint2*)((unsigned char*)xpt + (rowbase + (size_t)nn*64 + grp*4)*2) = val;
  }
}

// ---------------- MFMA implicit-GEMM 3x3x3 conv ----------------
__global__ __launch_bounds__(256) void k_conv3m(const bf16* __restrict__ xpt,
    const bf16* __restrict__ WB, const float* __restrict__ bias, float* __restrict__ Y)
{
  __shared__ uint4 smem4[2112];
  unsigned char* smb = (unsigned char*)smem4;
  float* smf = (float*)smem4;
  int t = threadIdx.x;
  int w = t >> 6, lane = t & 63;
  int r = lane & 15, q = lane >> 4;
  int qe = q & 1, qh = q >> 1;
  int a = blockIdx.x >> 3, b0 = (blockIdx.x & 7) * 4;

  int toff[14];
  #pragma unroll
  for (int tp = 0; tp < 14; ++tp) {
    int tap = 2*tp + qh;
    int da = tap/9, rem = tap - da*9, db = rem/3, dc = rem - db*3;
    toff[tp] = (tap < 27) ? (((da*6+db)*34 + dc)*48) : 0;
  }
  int F0 = (w*34 + r)*48 + qe*16;
  int F1 = F0 + 16*48;
  size_t bbyte = ((size_t)r*1792 + q*8)*2;

  f4v acc[2][4];
  #pragma unroll
  for (int mt=0;mt<2;mt++)
    #pragma unroll
    for (int nt=0;nt<4;nt++){ acc[mt][nt][0]=0.f; acc[mt][nt][1]=0.f; acc[mt][nt][2]=0.f; acc[mt][nt][3]=0.f; }

  for (int cc = 0; cc < 4; ++cc) {
    __syncthreads();
    uint4 tmp[5]; int dsts[5];
    #pragma unroll
    for (int k5 = 0; k5 < 5; ++k5) {
      int idx = t + k5*256;
      if (idx < 1224) {
        int row = idx / 68, rr = idx - row*68;
        int pc = rr >> 1, half = rr & 1;
        int par = row / 6;
        int pa = a + par, pb = b0 + row - par*6;
        size_t gb = ((size_t)((pa*34+pb)*34 + pc))*128 + cc*32 + half*16;
        tmp[k5] = *(const uint4*)((const unsigned char*)xpt + gb);
        dsts[k5] = (row*34 + pc)*3 + half;
      } else dsts[k5] = -1;
    }
    #pragma unroll
    for (int k5 = 0; k5 < 5; ++k5) if (dsts[k5] >= 0) smem4[dsts[k5]] = tmp[k5];
    __syncthreads();
    size_t kbase = (size_t)cc*448*2;
    #pragma unroll
    for (int tp = 0; tp < 14; ++tp) {
      s8v a0 = *(const s8v*)(smb + F0 + toff[tp]);
      s8v a1 = *(const s8v*)(smb + F1 + toff[tp]);
      size_t kb = bbyte + kbase + tp*64;
      s8v bv0 = *(const s8v*)((const unsigned char*)WB + kb);
      s8v bv1 = *(const s8v*)((const unsigned char*)WB + kb + 57344);
      s8v bv2 = *(const s8v*)((const unsigned char*)WB + kb + 114688);
      s8v bv3 = *(const s8v*)((const unsigned char*)WB + kb + 172032);
      acc[0][0] = __builtin_amdgcn_mfma_f32_16x16x32_bf16(a0, bv0, acc[0][0], 0, 0, 0);
      acc[0][1] = __builtin_amdgcn_mfma_f32_16x16x32_bf16(a0, bv1, acc[0][1], 0, 0, 0);
      acc[0][2] = __builtin_amdgcn_mfma_f32_16x16x32_bf16(a0, bv2, acc[0][2], 0, 0, 0);
      acc[0][3] = __builtin_amdgcn_mfma_f32_16x16x32_bf16(a0, bv3, acc[0][3], 0, 0, 0);
      acc[1][0] = __builtin_amdgcn_mfma_f32_16x16x32_bf16(a1, bv0, acc[1][0], 0, 0, 0);
      acc[1][1] = __builtin_amdgcn_mfma_f32_16x16x32_bf16(a1, bv1, acc[1][1], 0, 0, 0);
      acc[1][2] = __builtin_amdgcn_mfma_f32_16x16x32_bf16(a1, bv2, acc[1][2], 0, 0, 0);
      acc[1][3] = __builtin_amdgcn_mfma_f32_16x16x32_bf16(a1, bv3, acc[1][3], 0, 0, 0);
    }
  }
  __syncthreads();
  #pragma unroll
  for (int mt=0; mt<2; ++mt)
    #pragma unroll
    for (int nt=0; nt<4; ++nt)
      #pragma unroll
      for (int reg=0; reg<4; ++reg)
        smf[w*2112 + (nt*16+r)*33 + mt*16 + q*4 + reg] = acc[mt][nt][reg];
  __syncthreads();
  int c = lane & 31, cop = lane >> 5;
  size_t nb = (size_t)a*1024 + (size_t)(b0+w)*32;
  #pragma unroll
  for (int i=0;i<32;i++){
    int co = i*2 + cop;
    Y[(size_t)co*NTOT + nb + c] = smf[w*2112 + co*33 + c] + bias[co];
  }
}

// ---------------- batchnorm partial sums (atomic) ----------------
__global__ __launch_bounds__(256) void k_bnstats(const float* __restrict__ Y, float* __restrict__ stats)
{
  int ci = blockIdx.x & 63;
  int qy = blockIdx.x >> 6;
  const float* p = Y + (size_t)ci*NTOT + qy*8192;
  float s=0.f, ss=0.f;
  for (int i=threadIdx.x; i<2048; i+=256){
    float4 v = *(const float4*)(p + i*4);
    s += v.x+v.y+v.z+v.w;
    ss += v.x*v.x+v.y*v.y+v.z*v.z+v.w*v.w;
  }
  for (int o=32;o;o>>=1){ s += __shfl_down(s,o); ss += __shfl_down(ss,o); }
  __shared__ float rs[4], rss[4];
  int w = threadIdx.x>>6;
  if ((threadIdx.x&63)==0){ rs[w]=s; rss[w]=ss; }
  __syncthreads();
  if (threadIdx.x==0){
    atomicAdd(&stats[ci*2],   rs[0]+rs[1]+rs[2]+rs[3]);
    atomicAdd(&stats[ci*2+1], rss[0]+rss[1]+rss[2]+rss[3]);
  }
}

// ---------------- BN + residual + LReLU ----------------
__global__ __launch_bounds__(256) void k_bnres(const float* __restrict__ Y, const float* __restrict__ stats,
    const float* __restrict__ g, const float* __restrict__ be,
    const float* __restrict__ skipin, float* __restrict__ out)
{
  size_t idx = (size_t)blockIdx.x*256 + threadIdx.x;
  int ci = (int)(idx >> 15);
  float S = stats[ci*2], SS = stats[ci*2+1];
  float m = S*(1.f/NTOT);
  float rs = rsqrtf(SS*(1.f/NTOT) - m*m + 1e-5f);
  float v = (Y[idx]-m)*rs*g[ci] + be[ci] + skipin[idx];
  out[idx] = v>0.f ? v : 0.01f*v;
}

// ---------------- 1x1x1 conv + final residual -> fp32 out ----------------
__global__ __launch_bounds__(256) void k_conv1(const float* __restrict__ R, const float* __restrict__ w8t,
    const float* __restrict__ b8, const float* __restrict__ skip, float* __restrict__ out)
{
  __shared__ float wt[64][64];
  __shared__ float bs[64];
  int t = threadIdx.x;
  for (int idx=t; idx<4096; idx+=256) ((float*)wt)[idx] = w8t[idx];
  if (t<64) bs[t]=b8[t];
  __syncthreads();
  int lane = t&63, cg = t>>6;
  int n = blockIdx.x*64 + lane;
  float acc[16];
  #pragma unroll
  for (int j=0;j<16;j++) acc[j]=0.f;
  for (int ci=0; ci<64; ci++){
    float rv = R[(size_t)ci*NTOT + n];
    const float* wr = &wt[ci][cg*16];
    float4 wa = *(const float4*)(wr);
    float4 wb = *(const float4*)(wr+4);
    float4 wc = *(const float4*)(wr+8);
    float4 wd = *(const float4*)(wr+12);
    acc[0]+=rv*wa.x; acc[1]+=rv*wa.y; acc[2]+=rv*wa.z; acc[3]+=rv*wa.w;
    acc[4]+=rv*wb.x; acc[5]+=rv*wb.y; acc[6]+=rv*wb.z; acc[7]+=rv*wb.w;
    acc[8]+=rv*wc.x; acc[9]+=rv*wc.y; acc[10]+=rv*wc.z; acc[11]+=rv*wc.w;
    acc[12]+=rv*wd.x; acc[13]+=rv*wd.y; acc[14]+=rv*wd.z; acc[15]+=rv*wd.w;
  }
  #pragma unroll
  for (int j=0;j<16;j++){
    int co = cg*16+j;
    out[(size_t)co*NTOT + n] = acc[j] + bs[co] + skip[(size_t)co*NTOT+n];
  }
}

extern "C" void kernel_launch(void* const* d_in, const int* in_sizes, int n_in,
                              void* d_out, int out_size, void* d_ws, size_t ws_size,
                              hipStream_t stream) {
  (void)in_sizes; (void)n_in; (void)out_size; (void)ws_size;
  const float* x      = (const float*)d_in[0];
  const float* ln_g   = (const float*)d_in[1];
  const float* ln_b   = (const float*)d_in[2];
  const float* gamma  = (const float*)d_in[3];
  const float* qkvv_w = (const float*)d_in[4];
  const float* temp   = (const float*)d_in[5];
  const float* temp2  = (const float*)d_in[6];
  const float* rpb    = (const float*)d_in[7];
  const float* qemb   = (const float*)d_in[8];
  const float* op1w   = (const float*)d_in[9];
  const float* op1b   = (const float*)d_in[10];
  const float* op2w   = (const float*)d_in[11];
  const float* op2b   = (const float*)d_in[12];
  const float* c51_w1 = (const float*)d_in[13];
  const float* c51_b1 = (const float*)d_in[14];
  const float* c51_g1 = (const float*)d_in[15];
  const float* c51_be1= (const float*)d_in[16];
  const float* c51_w2 = (const float*)d_in[17];
  const float* c51_b2 = (const float*)d_in[18];
  const float* c51_g2 = (const float*)d_in[19];
  const float* c51_be2= (const float*)d_in[20];
  const float* c52_w1 = (const float*)d_in[21];
  const float* c52_b1 = (const float*)d_in[22];
  const float* c52_g1 = (const float*)d_in[23];
  const float* c52_be1= (const float*)d_in[24];
  const float* c52_w2 = (const float*)d_in[25];
  const float* c52_b2 = (const float*)d_in[26];
  const float* c52_g2 = (const float*)d_in[27];
  const float* c52_be2= (const float*)d_in[28];
  const float* c8_w   = (const float*)d_in[29];
  const float* c8_b   = (const float*)d_in[30];

  unsigned char* ws = (unsigned char*)d_ws;
  const size_t MB = 1u<<20;
  bf16*  qkvv = (bf16*)(ws + 0);              // 16 MB  (N,256)
  bf16*  xsa  = (bf16*)(ws + 16*MB);          // 4 MB
  bf16*  xca  = (bf16*)(ws + 20*MB);          // 4 MB
  float* skip = (float*)(ws + 24*MB);         // 8 MB
  float* stat = (float*)(ws + 32*MB);         // small
  float* G    = stat + 0;                     // 1024
  float* NQ   = stat + 1024;                  // 64
  float* NK   = stat + 1088;                  // 64
  float* ACA  = stat + 1152;                  // 1024
  float* BN   = stat + 2176;                  // 128
  bf16*  WB   = (bf16*)(ws + 32*MB + 65536);  // 4*64*1792 bf16 = 896KB
  float* w8t  = (float*)(ws + 32*MB + 65536 + 1835008); // 16KB
  bf16*  xpt  = (bf16*)(ws + 0);              // 5.03MB transposed padded (reuses qkvv)
  float* Y    = (float*)(ws + 6*MB);          // 8MB
  float* Y2   = (float*)(ws + 14*MB);         // 8MB
  float* R    = (float*)(ws + 35*MB);         // 8MB -> peak 43MB

  hipMemsetAsync(stat, 0, 1152*sizeof(float), stream);
  k_wprep<<<1792,256,0,stream>>>(c51_w1, c51_w2, c52_w1, c52_w2, c8_w, WB, w8t);
  k_qkvv<<<dim3(256,4),256,0,stream>>>(x, ln_g, ln_b, qkvv_w, qkvv);
  k_chanpart<<<dim3(64,4),256,0,stream>>>(qkvv, G, NQ, NK);
  k_chanfin<<<1,64,0,stream>>>(G, NQ, NK, temp, ACA);
  k_spatial<<<512,256,0,stream>>>(qkvv, ACA, temp2, rpb, qemb, xsa, xca);
  k_epilogue<<<512,256,0,stream>>>(x, xsa, xca, op1w, op1b, op2w, op2b, gamma, skip);
  // zero the padded borders once (interior rewritten by each k_padt)
  hipMemsetAsync(xpt, 0, (size_t)PADV*64*2, stream);
  // resblock 1
  k_padt<<<1024,256,0,stream>>>(skip, nullptr, nullptr, nullptr, xpt, 0);
  k_conv3m<<<256,256,0,stream>>>(xpt, WB + 0*114688, c51_b1, Y);
  hipMemsetAsync(BN, 0, 128*sizeof(float), stream);
  k_bnstats<<<256,256,0,stream>>>(Y, BN);
  k_padt<<<1024,256,0,stream>>>(Y, BN, c51_g1, c51_be1, xpt, 1);
  k_conv3m<<<256,256,0,stream>>>(xpt, WB + 1*114688, c51_b2, Y2);
  hipMemsetAsync(BN, 0, 128*sizeof(float), stream);
  k_bnstats<<<256,256,0,stream>>>(Y2, BN);
  k_bnres<<<8192,256,0,stream>>>(Y2, BN, c51_g2, c51_be2, skip, R);
  // resblock 2
  k_padt<<<1024,256,0,stream>>>(R, nullptr, nullptr, nullptr, xpt, 0);
  k_conv3m<<<256,256,0,stream>>>(xpt, WB + 2*114688, c52_b1, Y);
  hipMemsetAsync(BN, 0, 128*sizeof(float), stream);
  k_bnstats<<<256,256,0,stream>>>(Y, BN);
  k_padt<<<1024,256,0,stream>>>(Y, BN, c52_g1, c52_be1, xpt, 1);
  k_conv3m<<<256,256,0,stream>>>(xpt, WB + 3*114688, c52_b2, Y2);
  hipMemsetAsync(BN, 0, 128*sizeof(float), stream);
  k_bnstats<<<256,256,0,stream>>>(Y2, BN);
  k_bnres<<<8192,256,0,stream>>>(Y2, BN, c52_g2, c52_be2, R, R);
  // final 1x1x1 conv + residual
  k_conv1<<<512,256,0,stream>>>(R, w8t, c8_b, skip, (float*)d_out);
}

// Round 5
// 383.737 us; speedup vs baseline: 2.6483x; 1.1924x over previous
//
#include <hip/hip_runtime.h>
#include <hip/hip_bf16.h>

typedef __hip_bfloat16 bf16;
typedef __attribute__((ext_vector_type(8))) short s8v;
typedef __attribute__((ext_vector_type(4))) float f4v;

#define NTOT 32768   // 32*32*32 spatial positions
#define CH 64
#define PADV 39304   // 34*34*34
#define PROW 1156    // 34*34

__device__ __forceinline__ float bflo(unsigned int u){ union{unsigned int i;float f;}v; v.i=u<<16; return v.f; }
__device__ __forceinline__ float bfhi(unsigned int u){ union{unsigned int i;float f;}v; v.i=u&0xffff0000u; return v.f; }
__device__ __forceinline__ unsigned short f2bu(float f){ bf16 h = __float2bfloat16(f); unsigned short s; __builtin_memcpy(&s,&h,2); return s; }
__device__ __forceinline__ unsigned int pk2(float a, float b){ return (unsigned int)f2bu(a) | ((unsigned int)f2bu(b)<<16); }

__device__ __forceinline__ void load8(const bf16* p, float* o){
  uint4 u = *(const uint4*)p;
  o[0]=bflo(u.x); o[1]=bfhi(u.x); o[2]=bflo(u.y); o[3]=bfhi(u.y);
  o[4]=bflo(u.z); o[5]=bfhi(u.z); o[6]=bflo(u.w); o[7]=bfhi(u.w);
}
__device__ __forceinline__ void load16(const bf16* p, float* o){
  const uint4* q = (const uint4*)p;
  uint4 u0 = q[0], u1 = q[1];
  o[0]=bflo(u0.x); o[1]=bfhi(u0.x); o[2]=bflo(u0.y); o[3]=bfhi(u0.y);
  o[4]=bflo(u0.z); o[5]=bfhi(u0.z); o[6]=bflo(u0.w); o[7]=bfhi(u0.w);
  o[8]=bflo(u1.x); o[9]=bfhi(u1.x); o[10]=bflo(u1.y); o[11]=bfhi(u1.y);
  o[12]=bflo(u1.z); o[13]=bfhi(u1.z); o[14]=bflo(u1.w); o[15]=bfhi(u1.w);
}
__device__ __forceinline__ void store16(bf16* p, const float* v){
  uint4 u0, u1;
  u0.x=pk2(v[0],v[1]); u0.y=pk2(v[2],v[3]); u0.z=pk2(v[4],v[5]); u0.w=pk2(v[6],v[7]);
  u1.x=pk2(v[8],v[9]); u1.y=pk2(v[10],v[11]); u1.z=pk2(v[12],v[13]); u1.w=pk2(v[14],v[15]);
  uint4* q=(uint4*)p; q[0]=u0; q[1]=u1;
}

// ---------------- fused LayerNorm + qkvv GEMM ----------------
__global__ __launch_bounds__(256) void k_qkvv(const float* __restrict__ x,
    const float* __restrict__ lng, const float* __restrict__ lnb,
    const float* __restrict__ w, bf16* __restrict__ qkvv)
{
  __shared__ float A[64][132];
  __shared__ float Bt[64][68];
  __shared__ float mean_s[128], rstd_s[128];
  __shared__ float g_s[64], b_s[64];
  int t = threadIdx.x;
  int n0 = blockIdx.x * 128;
  int j0 = blockIdx.y * 64;
  for (int idx = t; idx < 64*32; idx += 256) {
    int c = idx >> 5, g = idx & 31;
    *(float4*)&A[c][g*4] = *(const float4*)(x + (size_t)c*NTOT + n0 + g*4);
  }
  for (int idx = t; idx < 64*16; idx += 256) {
    int jj = idx >> 4, g = idx & 15;
    *(float4*)&Bt[jj][g*4] = *(const float4*)(w + (size_t)(j0+jj)*64 + g*4);
  }
  if (t < 64) { g_s[t] = lng[t]; b_s[t] = lnb[t]; }
  __syncthreads();
  if (t < 128) {
    float s=0.f, ss=0.f;
    for (int c=0;c<64;c++){ float v=A[c][t]; s+=v; ss+=v*v; }
    float m = s*(1.f/64.f);
    float var = ss*(1.f/64.f) - m*m;
    mean_s[t]=m; rstd_s[t]=rsqrtf(var+1e-5f);
  }
  __syncthreads();
  for (int idx=t; idx<64*128; idx+=256){
    int c = idx >> 7, nn = idx & 127;
    A[c][nn] = (A[c][nn]-mean_s[nn])*rstd_s[nn]*g_s[c] + b_s[c];
  }
  __syncthreads();
  int tn = t & 15, tj = t >> 4;
  float acc[8][4];
  #pragma unroll
  for (int i=0;i<8;i++){ acc[i][0]=0;acc[i][1]=0;acc[i][2]=0;acc[i][3]=0; }
  for (int c=0;c<64;c++){
    float4 a0 = *(const float4*)&A[c][tn*8];
    float4 a1 = *(const float4*)&A[c][tn*8+4];
    float av[8] = {a0.x,a0.y,a0.z,a0.w,a1.x,a1.y,a1.z,a1.w};
    float bv[4];
    #pragma unroll
    for (int j=0;j<4;j++) bv[j] = Bt[tj*4+j][c];
    #pragma unroll
    for (int i=0;i<8;i++)
      #pragma unroll
      for (int j=0;j<4;j++) acc[i][j] += av[i]*bv[j];
  }
  #pragma unroll
  for (int i=0;i<8;i++){
    int n = n0 + tn*8 + i;
    ushort4 v;
    v.x = f2bu(acc[i][0]); v.y = f2bu(acc[i][1]); v.z = f2bu(acc[i][2]); v.w = f2bu(acc[i][3]);
    *(ushort4*)(qkvv + (size_t)n*256 + j0 + tj*4) = v;
  }
}

// ---------------- channel attention: partial Gram + norms ----------------
__global__ __launch_bounds__(256) void k_chanpart(const bf16* __restrict__ qkvv,
    float* __restrict__ G, float* __restrict__ NQ, float* __restrict__ NK)
{
  int h = blockIdx.y;
  int t = threadIdx.x; int d = t>>4, e = t&15;
  __shared__ float qs[128][16];
  __shared__ float ks[128][16];
  float acc=0.f, accq=0.f, acck=0.f;
  for (int stage=0; stage<4; ++stage){
    int n0 = blockIdx.x*512 + stage*128;
    __syncthreads();
    {
      int r = t>>1, half = t&1;
      const bf16* p = qkvv + (size_t)(n0+r)*256 + half*64 + h*16;
      float tmp[16]; load16(p, tmp);
      float* dst = half ? &ks[r][0] : &qs[r][0];
      #pragma unroll
      for (int i=0;i<16;i++) dst[i]=tmp[i];
    }
    __syncthreads();
    for (int i=0;i<128;i++){
      float qv = qs[i][d], kv = ks[i][e];
      acc += qv*kv;
      if (e==0) accq += qv*qv;
      if (e==1){ float kd = ks[i][d]; acck += kd*kd; }
    }
  }
  atomicAdd(&G[(h*16+d)*16+e], acc);
  if (e==0) atomicAdd(&NQ[h*16+d], accq);
  if (e==1) atomicAdd(&NK[h*16+d], acck);
}

__global__ void k_chanfin(const float* __restrict__ G, const float* __restrict__ NQ,
    const float* __restrict__ NK, const float* __restrict__ temp, float* __restrict__ ACA)
{
  int t = threadIdx.x; if (t>=64) return;
  int h = t>>4;
  float tp = temp[h];
  float nq = fmaxf(sqrtf(NQ[t]), 1e-12f);
  float s[16]; float mx=-3.0e38f;
  #pragma unroll
  for (int e=0;e<16;e++){
    float nk = fmaxf(sqrtf(NK[h*16+e]), 1e-12f);
    s[e] = G[t*16+e] / (nq*nk) * tp;
    mx = fmaxf(mx, s[e]);
  }
  float sum=0.f;
  #pragma unroll
  for (int e=0;e<16;e++){ s[e]=expf(s[e]-mx); sum+=s[e]; }
  float inv = 1.f/sum;
  #pragma unroll
  for (int e=0;e<16;e++) ACA[t*16+e] = s[e]*inv;
}

// ---------------- spatial window attention + channel apply ----------------
__global__ __launch_bounds__(256) void k_spatial(const bf16* __restrict__ qkvv,
    const float* __restrict__ ACA, const float* __restrict__ temp2,
    const float* __restrict__ rpb, const float* __restrict__ qemb,
    bf16* __restrict__ xsa, bf16* __restrict__ xca)
{
  __shared__ float aca_s[1024];
  __shared__ float rpb_s[108];
  __shared__ float qemb_s[64];
  int t = threadIdx.x;
  for (int i=t;i<1024;i+=256) aca_s[i]=ACA[i];
  if (t<108) rpb_s[t]=rpb[t];
  if (t<64) qemb_s[t]=qemb[t];
  __syncthreads();
  int lane = t & 63, h = t >> 6;
  int n = blockIdx.x*64 + lane;
  int a = n>>10, b=(n>>5)&31, c=n&31;
  float q[16]; load16(qkvv + (size_t)n*256 + h*16, q);
  float s2=0.f;
  #pragma unroll
  for (int d=0;d<16;d++) s2 += q[d]*q[d];
  float inv = 1.f/fmaxf(sqrtf(s2), 1e-12f);
  float st2 = log1pf(expf(temp2[h]));
  #pragma unroll
  for (int d=0;d<16;d++) q[d] = (q[d]*inv + qemb_s[h*16+d])*st2;
  float sc[27]; float mx = -3.0e38f;
  #pragma unroll
  for (int kk=0;kk<27;kk++){
    int da=kk/9-1, db=(kk/3)%3-1, dc=kk%3-1;
    int aa=a+da, bb=b+db, cc=c+dc;
    float s = -3.0e38f;
    if ((unsigned)aa<32u && (unsigned)bb<32u && (unsigned)cc<32u){
      int nn = n + da*1024 + db*32 + dc;
      float kv[16]; load16(qkvv + (size_t)nn*256 + 64 + h*16, kv);
      s = rpb_s[h*27+kk];
      #pragma unroll
      for (int d=0;d<16;d++) s += q[d]*kv[d];
    }
    sc[kk]=s; mx = fmaxf(mx, s);
  }
  float sum=0.f;
  #pragma unroll
  for (int kk=0;kk<27;kk++){ float e = expf(sc[kk]-mx); sc[kk]=e; sum+=e; }
  float invs = 1.f/sum;
  float o[16];
  #pragma unroll
  for (int d=0;d<16;d++) o[d]=0.f;
  #pragma unroll
  for (int kk=0;kk<27;kk++){
    int da=kk/9-1, db=(kk/3)%3-1, dc=kk%3-1;
    int aa=a+da, bb=b+db, cc=c+dc;
    if ((unsigned)aa<32u && (unsigned)bb<32u && (unsigned)cc<32u){
      int nn = n + da*1024 + db*32 + dc;
      float vv[16]; load16(qkvv + (size_t)nn*256 + 192 + h*16, vv);
      float p = sc[kk];
      #pragma unroll
      for (int d=0;d<16;d++) o[d] += p*vv[d];
    }
  }
  #pragma unroll
  for (int d=0;d<16;d++) o[d]*=invs;
  store16(xsa + ((size_t)h*NTOT + n)*16, o);
  float vca[16]; load16(qkvv + (size_t)n*256 + 128 + h*16, vca);
  float oc[16];
  #pragma unroll
  for (int d=0;d<16;d++){
    float s=0.f;
    #pragma unroll
    for (int e=0;e<16;e++) s += aca_s[(h*16+d)*16+e]*vca[e];
    oc[d]=s;
  }
  store16(xca + (size_t)n*64 + h*16, oc);
}

// ---------------- projections + gamma residual -> skip (C,N) fp32 ----------------
__global__ __launch_bounds__(256) void k_epilogue(const float* __restrict__ x,
    const bf16* __restrict__ xsa, const bf16* __restrict__ xca,
    const float* __restrict__ op1w, const float* __restrict__ op1b,
    const float* __restrict__ op2w, const float* __restrict__ op2b,
    const float* __restrict__ gamma, float* __restrict__ skip)
{
  __shared__ float xs_s[64][68];
  __shared__ float xc_s[64][68];
  int t = threadIdx.x;
  int n0 = blockIdx.x * 64;
  #pragma unroll
  for (int it=0; it<2; ++it){
    int idx = t + it*256;
    int p = idx >> 3, cg = idx & 7;
    float a8[8], c8[8];
    load8(xsa + (size_t)(n0+p)*64 + cg*8, a8);
    load8(xca + (size_t)(n0+p)*64 + cg*8, c8);
    #pragma unroll
    for (int i=0;i<8;i++){ xs_s[p][cg*8+i]=a8[i]; xc_s[p][cg*8+i]=c8[i]; }
  }
  int co = t & 63, pg = t >> 6;
  const float* wrow = (co < 32) ? (op1w + (size_t)co*64) : (op2w + (size_t)(co-32)*64);
  float wreg[64];
  #pragma unroll
  for (int i=0;i<16;i++) *(float4*)&wreg[i*4] = *(const float4*)(wrow + i*4);
  float bv = (co<32) ? op1b[co] : op2b[co-32];
  float gv = gamma[co];
  __syncthreads();
  const float* xt = (co<32) ? &xs_s[0][0] : &xc_s[0][0];
  float out16[16];
  #pragma unroll
  for (int i=0;i<16;i++){
    int p = pg*16 + i;
    const float* xr = xt + p*68;
    float s = bv;
    #pragma unroll
    for (int k4=0;k4<16;k4++){
      float4 xv = *(const float4*)(xr + k4*4);
      s += wreg[k4*4]*xv.x + wreg[k4*4+1]*xv.y + wreg[k4*4+2]*xv.z + wreg[k4*4+3]*xv.w;
    }
    out16[i] = s;
  }
  size_t base = (size_t)co*NTOT + n0 + pg*16;
  #pragma unroll
  for (int i4=0;i4<4;i4++){
    float4 xv = *(const float4*)(x + base + i4*4);
    float4 ov;
    ov.x = xv.x + gv*out16[i4*4];
    ov.y = xv.y + gv*out16[i4*4+1];
    ov.z = xv.z + gv*out16[i4*4+2];
    ov.w = xv.w + gv*out16[i4*4+3];
    *(float4*)(skip + base + i4*4) = ov;
  }
}

// ---------------- conv weight prep ----------------
// New WB layout: element idx = ((((conv*4+cc)*14+tp)*4+nt)*4+q)*128 + rr*8 + j
// -> per (conv,cc,tp,nt): one 1KB lane-contiguous block (addr = base + lane*16)
__global__ void k_wprep(const float* __restrict__ wA, const float* __restrict__ wB_,
    const float* __restrict__ wC, const float* __restrict__ wD,
    const float* __restrict__ w8, bf16* __restrict__ WB, float* __restrict__ w8t)
{
  int idx = blockIdx.x*256 + threadIdx.x;
  if (idx < 458752){
    int j = idx & 7;
    int rr = (idx>>3) & 15;
    int q = (idx>>7) & 3;
    int nt = (idx>>9) & 3;
    int rest = idx >> 11;
    int tp = rest % 14;
    int rest2 = rest / 14;
    int cc = rest2 & 3;
    int conv = rest2 >> 2;
    int co = nt*16 + rr;
    int tap = 2*tp + (q>>1);
    int ci = cc*16 + (q&1)*8 + j;
    const float* src = conv==0?wA:conv==1?wB_:conv==2?wC:wD;
    float v = (tap < 27) ? src[((size_t)co*64 + ci)*27 + tap] : 0.f;
    WB[idx] = __float2bfloat16(v);
  }
  if (idx < 4096){ int ci = idx>>6, co = idx&63; w8t[ci*64+co] = w8[(size_t)co*64+ci]; }
}

// ---------------- pad+transpose (+optional BN+LReLU): (C,N) fp32 -> xpt[34^3][64] bf16 ----------------
__global__ __launch_bounds__(256) void k_padt(const float* __restrict__ src,
    const float* __restrict__ stats, const float* __restrict__ g, const float* __restrict__ be,
    bf16* __restrict__ xpt, int mode)
{
  __shared__ bf16 tile[32][68];
  int t = threadIdx.x;
  int n0 = blockIdx.x * 32;
  int nl = t & 31, cig = t >> 5;
  int n = n0 + nl;
  #pragma unroll
  for (int i=0;i<8;i++){
    int ci = cig*8 + i;
    float v = src[(size_t)ci*NTOT + n];
    if (mode){
      float S = stats[ci*2], SS = stats[ci*2+1];
      float m = S*(1.f/NTOT);
      float rs = rsqrtf(SS*(1.f/NTOT) - m*m + 1e-5f);
      v = (v-m)*rs*g[ci] + be[ci];
      v = v>0.f ? v : 0.01f*v;
    }
    tile[nl][ci] = __float2bfloat16(v);
  }
  __syncthreads();
  int a = n0 >> 10, b = (n0 >> 5) & 31;
  size_t rowbase = ((size_t)((a+1)*34 + (b+1))*34 + 1)*64;
  #pragma unroll
  for (int k2=0;k2<2;k2++){
    int j = t + k2*256;
    int nn = j >> 4, grp = j & 15;
    uint2 val = *(const uint2*)&tile[nn][grp*4];
    *(uint2*)((unsigned char*)xpt + (rowbase + (size_t)nn*64 + grp*4)*2) = val;
  }
}

// ---------------- MFMA implicit-GEMM 3x3x3 conv (K-split waves) ----------------
// grid 512: a = bx>>4, b0 = (bx&15)*2.  Block: 64 pos x 64 co.  Wave w = K-chunk w.
__global__ __launch_bounds__(256, 2) void k_conv3m(const bf16* __restrict__ xpt,
    const bf16* __restrict__ WB, const float* __restrict__ bias, float* __restrict__ Y)
{
  __shared__ float smf[17408];               // 69632 B (A slab uses 58752 B)
  unsigned char* smb = (unsigned char*)smf;
  int t = threadIdx.x;
  int w = t >> 6, lane = t & 63;
  int r = lane & 15, q = lane >> 4;
  int qe = q & 1, qh = q >> 1;
  int a = blockIdx.x >> 4, b0 = (blockIdx.x & 15) * 2;

  // ---- stage A slab: 408 positions x 128B (all 64 ci), LDS stride 144B ----
  {
    uint4 tmp[13];
    #pragma unroll
    for (int k=0;k<13;k++){
      int idx = t + k*256;
      if (idx < 3264){
        int pos = idx >> 3, h = idx & 7;
        int par = pos/136, rem = pos - par*136;
        int pbr = rem/34, pc = rem - pbr*34;
        size_t gb = (((size_t)(a+par)*34 + (b0+pbr))*34 + pc)*128 + h*16;
        tmp[k] = *(const uint4*)((const unsigned char*)xpt + gb);
      }
    }
    #pragma unroll
    for (int k=0;k<13;k++){
      int idx = t + k*256;
      if (idx < 3264){
        int pos = idx >> 3, h = idx & 7;
        *(uint4*)(smb + pos*144 + h*16) = tmp[k];
      }
    }
  }

  int toff[14];
  #pragma unroll
  for (int tp=0;tp<14;++tp){
    int tap = 2*tp + qh;
    int da = tap/9, rem = tap - da*9, db = rem/3, dc = rem - db*3;
    toff[tp] = (tap<27) ? (((da*4+db)*34 + dc)*144) : 0;
  }
  int F[4];
  #pragma unroll
  for (int mt=0;mt<4;mt++) F[mt] = (((mt>>1)*34 + (mt&1)*16 + r)*144) + w*32 + qe*16;
  const unsigned char* wbp = (const unsigned char*)WB + (size_t)w*57344 + lane*16;

  f4v acc[4][4];
  #pragma unroll
  for (int mt=0;mt<4;mt++)
    #pragma unroll
    for (int nt=0;nt<4;nt++){ acc[mt][nt][0]=0.f; acc[mt][nt][1]=0.f; acc[mt][nt][2]=0.f; acc[mt][nt][3]=0.f; }

  __syncthreads();

  s8v aC[4], bC[4];
  #pragma unroll
  for (int mt=0;mt<4;mt++) aC[mt] = *(const s8v*)(smb + F[mt] + toff[0]);
  #pragma unroll
  for (int nt=0;nt<4;nt++) bC[nt] = *(const s8v*)(wbp + nt*1024);

  #pragma unroll
  for (int tp=0; tp<14; ++tp){
    s8v aN[4], bN[4];
    if (tp < 13){
      #pragma unroll
      for (int mt=0;mt<4;mt++) aN[mt] = *(const s8v*)(smb + F[mt] + toff[tp+1]);
      #pragma unroll
      for (int nt=0;nt<4;nt++) bN[nt] = *(const s8v*)(wbp + (tp+1)*4096 + nt*1024);
    }
    #pragma unroll
    for (int mt=0;mt<4;mt++)
      #pragma unroll
      for (int nt=0;nt<4;nt++)
        acc[mt][nt] = __builtin_amdgcn_mfma_f32_16x16x32_bf16(aC[mt], bC[nt], acc[mt][nt], 0, 0, 0);
    if (tp < 13){
      #pragma unroll
      for (int mt=0;mt<4;mt++) aC[mt] = aN[mt];
      #pragma unroll
      for (int nt=0;nt<4;nt++) bC[nt] = bN[nt];
    }
  }

  // ---- write per-wave partials to LDS: region w*4352 floats, [co][pos] stride 68 ----
  __syncthreads();
  #pragma unroll
  for (int mt=0;mt<4;mt++)
    #pragma unroll
    for (int nt=0;nt<4;nt++)
      *(float4*)&smf[w*4352 + (nt*16+r)*68 + mt*16 + q*4] = *(float4*)&acc[mt][nt];
  __syncthreads();

  // ---- reduce 4 partials + bias -> Y ----
  int co = t >> 2, pg = t & 3;
  float bv = bias[co];
  #pragma unroll
  for (int i4=0;i4<4;i4++){
    int p = pg*16 + i4*4;
    float4 s0 = *(const float4*)&smf[0*4352 + co*68 + p];
    float4 s1 = *(const float4*)&smf[1*4352 + co*68 + p];
    float4 s2 = *(const float4*)&smf[2*4352 + co*68 + p];
    float4 s3 = *(const float4*)&smf[3*4352 + co*68 + p];
    float4 ov;
    ov.x = s0.x+s1.x+s2.x+s3.x+bv;
    ov.y = s0.y+s1.y+s2.y+s3.y+bv;
    ov.z = s0.z+s1.z+s2.z+s3.z+bv;
    ov.w = s0.w+s1.w+s2.w+s3.w+bv;
    *(float4*)(Y + (size_t)co*NTOT + (size_t)a*1024 + (size_t)(b0 + (p>>5))*32 + (p&31)) = ov;
  }
}

// ---------------- batchnorm partial sums (atomic) ----------------
__global__ __launch_bounds__(256) void k_bnstats(const float* __restrict__ Y, float* __restrict__ stats)
{
  int ci = blockIdx.x & 63;
  int qy = blockIdx.x >> 6;
  const float* p = Y + (size_t)ci*NTOT + qy*8192;
  float s=0.f, ss=0.f;
  for (int i=threadIdx.x; i<2048; i+=256){
    float4 v = *(const float4*)(p + i*4);
    s += v.x+v.y+v.z+v.w;
    ss += v.x*v.x+v.y*v.y+v.z*v.z+v.w*v.w;
  }
  for (int o=32;o;o>>=1){ s += __shfl_down(s,o); ss += __shfl_down(ss,o); }
  __shared__ float rs[4], rss[4];
  int w = threadIdx.x>>6;
  if ((threadIdx.x&63)==0){ rs[w]=s; rss[w]=ss; }
  __syncthreads();
  if (threadIdx.x==0){
    atomicAdd(&stats[ci*2],   rs[0]+rs[1]+rs[2]+rs[3]);
    atomicAdd(&stats[ci*2+1], rss[0]+rss[1]+rss[2]+rss[3]);
  }
}

// ---------------- BN + residual + LReLU ----------------
__global__ __launch_bounds__(256) void k_bnres(const float* __restrict__ Y, const float* __restrict__ stats,
    const float* __restrict__ g, const float* __restrict__ be,
    const float* __restrict__ skipin, float* __restrict__ out)
{
  size_t idx = (size_t)blockIdx.x*256 + threadIdx.x;
  int ci = (int)(idx >> 15);
  float S = stats[ci*2], SS = stats[ci*2+1];
  float m = S*(1.f/NTOT);
  float rs = rsqrtf(SS*(1.f/NTOT) - m*m + 1e-5f);
  float v = (Y[idx]-m)*rs*g[ci] + be[ci] + skipin[idx];
  out[idx] = v>0.f ? v : 0.01f*v;
}

// ---------------- 1x1x1 conv + final residual -> fp32 out ----------------
__global__ __launch_bounds__(256) void k_conv1(const float* __restrict__ R, const float* __restrict__ w8t,
    const float* __restrict__ b8, const float* __restrict__ skip, float* __restrict__ out)
{
  __shared__ float wt[64][64];
  __shared__ float bs[64];
  int t = threadIdx.x;
  for (int idx=t; idx<4096; idx+=256) ((float*)wt)[idx] = w8t[idx];
  if (t<64) bs[t]=b8[t];
  __syncthreads();
  int lane = t&63, cg = t>>6;
  int n = blockIdx.x*64 + lane;
  float acc[16];
  #pragma unroll
  for (int j=0;j<16;j++) acc[j]=0.f;
  for (int ci=0; ci<64; ci++){
    float rv = R[(size_t)ci*NTOT + n];
    const float* wr = &wt[ci][cg*16];
    float4 wa = *(const float4*)(wr);
    float4 wb = *(const float4*)(wr+4);
    float4 wc = *(const float4*)(wr+8);
    float4 wd = *(const float4*)(wr+12);
    acc[0]+=rv*wa.x; acc[1]+=rv*wa.y; acc[2]+=rv*wa.z; acc[3]+=rv*wa.w;
    acc[4]+=rv*wb.x; acc[5]+=rv*wb.y; acc[6]+=rv*wb.z; acc[7]+=rv*wb.w;
    acc[8]+=rv*wc.x; acc[9]+=rv*wc.y; acc[10]+=rv*wc.z; acc[11]+=rv*wc.w;
    acc[12]+=rv*wd.x; acc[13]+=rv*wd.y; acc[14]+=rv*wd.z; acc[15]+=rv*wd.w;
  }
  #pragma unroll
  for (int j=0;j<16;j++){
    int co = cg*16+j;
    out[(size_t)co*NTOT + n] = acc[j] + bs[co] + skip[(size_t)co*NTOT+n];
  }
}

extern "C" void kernel_launch(void* const* d_in, const int* in_sizes, int n_in,
                              void* d_out, int out_size, void* d_ws, size_t ws_size,
                              hipStream_t stream) {
  (void)in_sizes; (void)n_in; (void)out_size; (void)ws_size;
  const float* x      = (const float*)d_in[0];
  const float* ln_g   = (const float*)d_in[1];
  const float* ln_b   = (const float*)d_in[2];
  const float* gamma  = (const float*)d_in[3];
  const float* qkvv_w = (const float*)d_in[4];
  const float* temp   = (const float*)d_in[5];
  const float* temp2  = (const float*)d_in[6];
  const float* rpb    = (const float*)d_in[7];
  const float* qemb   = (const float*)d_in[8];
  const float* op1w   = (const float*)d_in[9];
  const float* op1b   = (const float*)d_in[10];
  const float* op2w   = (const float*)d_in[11];
  const float* op2b   = (const float*)d_in[12];
  const float* c51_w1 = (const float*)d_in[13];
  const float* c51_b1 = (const float*)d_in[14];
  const float* c51_g1 = (const float*)d_in[15];
  const float* c51_be1= (const float*)d_in[16];
  const float* c51_w2 = (const float*)d_in[17];
  const float* c51_b2 = (const float*)d_in[18];
  const float* c51_g2 = (const float*)d_in[19];
  const float* c51_be2= (const float*)d_in[20];
  const float* c52_w1 = (const float*)d_in[21];
  const float* c52_b1 = (const float*)d_in[22];
  const float* c52_g1 = (const float*)d_in[23];
  const float* c52_be1= (const float*)d_in[24];
  const float* c52_w2 = (const float*)d_in[25];
  const float* c52_b2 = (const float*)d_in[26];
  const float* c52_g2 = (const float*)d_in[27];
  const float* c52_be2= (const float*)d_in[28];
  const float* c8_w   = (const float*)d_in[29];
  const float* c8_b   = (const float*)d_in[30];

  unsigned char* ws = (unsigned char*)d_ws;
  const size_t MB = 1u<<20;
  bf16*  qkvv = (bf16*)(ws + 0);              // 16 MB  (N,256)
  bf16*  xsa  = (bf16*)(ws + 16*MB);          // 4 MB
  bf16*  xca  = (bf16*)(ws + 20*MB);          // 4 MB
  float* skip = (float*)(ws + 24*MB);         // 8 MB
  float* stat = (float*)(ws + 32*MB);         // small
  float* G    = stat + 0;                     // 1024
  float* NQ   = stat + 1024;                  // 64
  float* NK   = stat + 1088;                  // 64
  float* ACA  = stat + 1152;                  // 1024
  float* BN   = stat + 2176;                  // 128
  bf16*  WB   = (bf16*)(ws + 32*MB + 65536);  // 4*114688 bf16 = 896KB
  float* w8t  = (float*)(ws + 32*MB + 65536 + 1835008); // 16KB
  bf16*  xpt  = (bf16*)(ws + 0);              // 5.03MB transposed padded (reuses qkvv)
  float* Y    = (float*)(ws + 6*MB);          // 8MB
  float* Y2   = (float*)(ws + 14*MB);         // 8MB
  float* R    = (float*)(ws + 35*MB);         // 8MB -> peak 43MB

  hipMemsetAsync(stat, 0, 1152*sizeof(float), stream);
  k_wprep<<<1792,256,0,stream>>>(c51_w1, c51_w2, c52_w1, c52_w2, c8_w, WB, w8t);
  k_qkvv<<<dim3(256,4),256,0,stream>>>(x, ln_g, ln_b, qkvv_w, qkvv);
  k_chanpart<<<dim3(64,4),256,0,stream>>>(qkvv, G, NQ, NK);
  k_chanfin<<<1,64,0,stream>>>(G, NQ, NK, temp, ACA);
  k_spatial<<<512,256,0,stream>>>(qkvv, ACA, temp2, rpb, qemb, xsa, xca);
  k_epilogue<<<512,256,0,stream>>>(x, xsa, xca, op1w, op1b, op2w, op2b, gamma, skip);
  // zero the padded borders once (interior rewritten by each k_padt)
  hipMemsetAsync(xpt, 0, (size_t)PADV*64*2, stream);
  // resblock 1
  k_padt<<<1024,256,0,stream>>>(skip, nullptr, nullptr, nullptr, xpt, 0);
  k_conv3m<<<512,256,0,stream>>>(xpt, WB + 0*114688, c51_b1, Y);
  hipMemsetAsync(BN, 0, 128*sizeof(float), stream);
  k_bnstats<<<256,256,0,stream>>>(Y, BN);
  k_padt<<<1024,256,0,stream>>>(Y, BN, c51_g1, c51_be1, xpt, 1);
  k_conv3m<<<512,256,0,stream>>>(xpt, WB + 1*114688, c51_b2, Y2);
  hipMemsetAsync(BN, 0, 128*sizeof(float), stream);
  k_bnstats<<<256,256,0,stream>>>(Y2, BN);
  k_bnres<<<8192,256,0,stream>>>(Y2, BN, c51_g2, c51_be2, skip, R);
  // resblock 2
  k_padt<<<1024,256,0,stream>>>(R, nullptr, nullptr, nullptr, xpt, 0);
  k_conv3m<<<512,256,0,stream>>>(xpt, WB + 2*114688, c52_b1, Y);
  hipMemsetAsync(BN, 0, 128*sizeof(float), stream);
  k_bnstats<<<256,256,0,stream>>>(Y, BN);
  k_padt<<<1024,256,0,stream>>>(Y, BN, c52_g1, c52_be1, xpt, 1);
  k_conv3m<<<512,256,0,stream>>>(xpt, WB + 3*114688, c52_b2, Y2);
  hipMemsetAsync(BN, 0, 128*sizeof(float), stream);
  k_bnstats<<<256,256,0,stream>>>(Y2, BN);
  k_bnres<<<8192,256,0,stream>>>(Y2, BN, c52_g2, c52_be2, R, R);
  // final 1x1x1 conv + residual
  k_conv1<<<512,256,0,stream>>>(R, w8t, c8_b, skip, (float*)d_out);
}